// Round 2
// baseline (336.395 us; speedup 1.0000x reference)
//
#include <hip/hip_runtime.h>
#include <hip/hip_bf16.h>

// GCN 2-layer forward. Pipeline (6 kernels):
//   prep          : zero bucket cursors + W1,W2 -> bf16 transposed (Wt[n][k])
//   bin_edges     : edges -> bucket-strided esrc (int) + edloc (uchar local dst)
//   build_csr     : per-bucket LDS histogram/prefix -> dinv, rbeg/rend, csr,
//                   AND u = bf16(z * dinv[:,None])
//   aggregate PRE : agg1_d = bf16(u_d + sum u_s)   (uniform-32 masked gather)
//   gemm12_mfma   : x1 = relu(dinv*(agg1@W1)+b1) in LDS (bf16);
//                   hs2 = bf16(dinv*(x1@W2))      (both GEMMs on MFMA)
//   aggregate POST: out_d = dinv_d*(hs2_d + sum hs2_s) + b2  (fp32 NT store)
//
// Round-2 notes:
//  - Fusion of aggregate+GEMM REGRESSED (62.6us vs 43.8+12): barrier-induced
//    wave idling + 3WG/CU LDS cap during gather. Reverted to split kernels.
//  - Aggregate is LATENCY-bound (L2-side 4.7TB/s = 14% of L2 BW, VALUBusy 20%).
//    Old 16/4/1-wide tail loops gave ~3.9 dependent waits/row (deg~Poisson(16)).
//    New: uniform 32-wide batches, CSR index clamped to end-1 (scalar min; tail
//    dupes are same-line L1 hits), overhang masked to 0.0 -> 1 wait for 98% rows.
//  - hs2 stays a NORMAL store (it is the layer-2 gather table; keep L2-warm).
//    Only the final out is NT.

#define WAVE 64
#define BSHIFT 8
#define NPB 256              // nodes per bucket
#define CAP 5120             // max edges per bucket (mean 4096, +16 sigma)
#define CH 4096              // edges per WG in bin_edges
#define NBMAX 512

typedef __attribute__((ext_vector_type(8))) short bf16x8;
typedef __attribute__((ext_vector_type(4))) float f32x4;

__device__ inline float bf16_to_f32(unsigned short h) {
    return __uint_as_float(((unsigned int)h) << 16);
}
__device__ inline unsigned short f32_to_bf16(float f) {
    unsigned int x = __float_as_uint(f);
    return (unsigned short)((x + 0x7FFFu + ((x >> 16) & 1u)) >> 16);   // RNE
}

// Uniform-32 masked gather: acc += sum of bf16 rows hs[csr[e]][lane].
// All 32 loads issued unconditionally per batch (indices clamped to last valid
// edge -> in-bounds, tail dupes hit L1), overhang masked to 0.0 via cndmask.
// One vmcnt wait per 32 edges -> MLP 32 even for short rows.
__device__ inline float gather_rows32(const unsigned short* __restrict__ hs,
                                      const int* __restrict__ csr,
                                      int beg, int end, int lane, float acc)
{
    const int last = end - 1;            // valid whenever the loop body runs
    for (int e = beg; e < end; e += 32) {
        int s[32];
#pragma unroll
        for (int j = 0; j < 32; ++j) {
            int idx = e + j;
            s[j] = csr[idx < end ? idx : last];   // scalar clamp (node-uniform)
        }
        float v[32];
#pragma unroll
        for (int j = 0; j < 32; ++j)
            v[j] = bf16_to_f32(hs[(size_t)s[j] * 64 + lane]);
#pragma unroll
        for (int j = 0; j < 32; ++j)
            v[j] = (e + j < end) ? v[j] : 0.0f;   // wave-uniform mask, no branch
        // in-place pairwise tree (5 levels)
#pragma unroll
        for (int w = 16; w >= 1; w >>= 1)
#pragma unroll
            for (int j = 0; j < 32; ++j) {
                if (j < w) v[j] = v[2 * j] + v[2 * j + 1];
            }
        acc += v[0];
    }
    return acc;
}

// ---------------- prep: zero cursors + W -> bf16 transposed ----------------
__global__ void prep(const float* __restrict__ W1, const float* __restrict__ W2,
                     unsigned short* __restrict__ W1t, unsigned short* __restrict__ W2t,
                     int* __restrict__ bcursor, int NB)
{
    int i = blockIdx.x * blockDim.x + threadIdx.x;
    if (i < NB) bcursor[i] = 0;
    if (i < 128 * 64) {          // W1t[n][k] = W1[k][n]  (W1 is [64][128])
        int n = i >> 6, k = i & 63;
        W1t[i] = f32_to_bf16(W1[k * 128 + n]);
    }
    if (i < 64 * 128) {          // W2t[n][k] = W2[k][n]  (W2 is [128][64])
        int n = i >> 7, k = i & 127;
        W2t[i] = f32_to_bf16(W2[k * 64 + n]);
    }
}

// ---------------- bin_edges: scatter edges into bucket-strided esrc/edloc ---
__global__ __launch_bounds__(256) void bin_edges(
        const int* __restrict__ src, const int* __restrict__ dst,
        int* __restrict__ bcursor, int* __restrict__ esrc,
        unsigned char* __restrict__ edloc, int E, int NB)
{
    __shared__ int hist[NBMAX];
    __shared__ int cur[NBMAX];
    const int t  = threadIdx.x;
    const int e0 = blockIdx.x * CH;

    for (int b = t; b < NB; b += 256) hist[b] = 0;
    __syncthreads();

#pragma unroll
    for (int j = 0; j < CH / 256; ++j) {
        int e = e0 + j * 256 + t;
        if (e < E) atomicAdd(&hist[dst[e] >> BSHIFT], 1);
    }
    __syncthreads();

    for (int b = t; b < NB; b += 256) {
        int c = hist[b];
        cur[b] = (c > 0) ? atomicAdd(&bcursor[b], c) : 0;
    }
    __syncthreads();

#pragma unroll
    for (int j = 0; j < CH / 256; ++j) {
        int e = e0 + j * 256 + t;
        if (e < E) {
            int s = __builtin_nontemporal_load(&src[e]);   // read once -> NT
            int d = dst[e];                                 // L1/L2-warm from pass 1
            int b = d >> BSHIFT;
            int pos = atomicAdd(&cur[b], 1);
            size_t idx = (size_t)b * CAP + pos;
            esrc[idx]  = s;
            edloc[idx] = (unsigned char)(d & (NPB - 1));
        }
    }
}

// ---------------- build_csr + fused u = bf16(z*dinv) ----------------
__global__ __launch_bounds__(256) void build_csr(
        const int* __restrict__ esrc, const unsigned char* __restrict__ edloc,
        const int* __restrict__ bcursor,
        const float* __restrict__ z, float* __restrict__ dinv,
        int* __restrict__ rbeg, int* __restrict__ rend,
        int* __restrict__ csr, unsigned short* __restrict__ u, int N)
{
    __shared__ int   h[NPB];
    __shared__ int   tmp[NPB];
    __shared__ float sdv[NPB];
    const int t   = threadIdx.x;
    const int b   = blockIdx.x;
    const int n0  = b << BSHIFT;
    const int cnt = bcursor[b];
    const size_t base = (size_t)b * CAP;

    h[t] = 0;
    __syncthreads();

    for (int i = t; i < cnt; i += 256)
        atomicAdd(&h[edloc[base + i]], 1);
    __syncthreads();

    int deg = h[t];
    tmp[t] = deg;
    __syncthreads();
    for (int off = 1; off < 256; off <<= 1) {
        int x = (t >= off) ? tmp[t - off] : 0;
        __syncthreads();
        tmp[t] += x;
        __syncthreads();
    }
    int st = tmp[t] - deg;

    int node = n0 + t;
    float di = rsqrtf((float)deg + 1.0f);
    sdv[t] = di;
    if (node < N) {
        dinv[node] = di;
        rbeg[node] = (int)base + st;
        rend[node] = (int)base + st + deg;
    }
    h[t] = st;
    __syncthreads();   // covers h-cursor reset and sdv visibility

    for (int i = t; i < cnt; i += 256) {
        int dl = edloc[base + i];
        int p = atomicAdd(&h[dl], 1);
        csr[base + p] = __builtin_nontemporal_load(&esrc[base + i]);
    }

    // fused scale: u rows for this bucket (16 threads per row, float4 reads)
    const int nloc = (N - n0 < NPB) ? (N - n0) : NPB;
    for (int i = t; i < nloc * 16; i += 256) {
        int r = i >> 4, kq = i & 15;
        float d2 = sdv[r];
        const f32x4* zr = (const f32x4*)(z + (size_t)(n0 + r) * 64);
        f32x4 v = __builtin_nontemporal_load(zr + kq);     // z read once -> NT
        ushort4 o;
        o.x = f32_to_bf16(v[0] * d2);
        o.y = f32_to_bf16(v[1] * d2);
        o.z = f32_to_bf16(v[2] * d2);
        o.w = f32_to_bf16(v[3] * d2);
        ((ushort4*)(u + (size_t)(n0 + r) * 64))[kq] = o;
    }
}

// ---------------- aggregate (F=64, bf16 rows), one wave per node -----------
// PRE  (POST=false): out = bf16(hs_d + sum hs_s)        -> ushort* (normal store:
//                    agg1 is re-read linearly by the GEMM right after, keep in L2)
// POST (POST=true):  out = dinv_d*(hs_d + sum hs_s) + b -> float* (NT store:
//                    out never re-read; protect L2 ways for the gather table)
template<bool POST>
__global__ __launch_bounds__(256) void aggregate64_bf16(
        const unsigned short* __restrict__ hs, const int* __restrict__ rbeg,
        const int* __restrict__ rend, const int* __restrict__ csr,
        const float* __restrict__ dinv, const float* __restrict__ b,
        void* __restrict__ out_, int N)
{
    int node = (int)((blockIdx.x * (size_t)blockDim.x + threadIdx.x) >> 6);
    int lane = threadIdx.x & 63;
    if (node >= N) return;
    node = __builtin_amdgcn_readfirstlane(node);   // wave-uniform -> scalar loads

    const int beg = rbeg[node];
    const int end = rend[node];

    float acc = bf16_to_f32(hs[(size_t)node * 64 + lane]);   // self-loop term
    acc = gather_rows32(hs, csr, beg, end, lane, acc);

    if (POST) {
        float o = dinv[node] * acc + b[lane];
        __builtin_nontemporal_store(o, &((float*)out_)[(size_t)node * 64 + lane]);
    } else {
        ((unsigned short*)out_)[(size_t)node * 64 + lane] = f32_to_bf16(acc);
    }
}

// ---------------- fused dual GEMM on MFMA ----------------
// Per 32-row tile:
//   phase 1: x1 = relu(dinv*(agg1@W1)+b1)  -> LDS bf16 (A-operand layout)
//   phase 2: hs2 = bf16(dinv*(x1@W2))      -> global (normal store; gather table)
// mfma_f32_16x16x32_bf16 layouts (HW-verified, learn_hip m89/m91/m120):
//   A: lane holds A[m=lane&15][k = (lane>>4)*8 + j]  (8 contiguous bf16)
//   B: lane holds B[k=(lane>>4)*8+j][n=lane&15]  -> stage W transposed Wt[n][k]
//   C/D: col = lane&15, row = (lane>>4)*4 + reg
// LDS ~49.3 KB -> 3 WGs/CU. Padded strides (72/136 ushorts) keep reads ~2-way.
#define TILE 32
#define W1T_ST 72
#define W2T_ST 136
#define A_ST   72
#define X1_ST  136

__global__ __launch_bounds__(256) void gemm12_mfma(
        const unsigned short* __restrict__ agg1,   // bf16 [N][64]
        const unsigned short* __restrict__ W1t,    // bf16 [128][64]  (n-major)
        const float* __restrict__ b1,              // [128]
        const unsigned short* __restrict__ W2t,    // bf16 [64][128]  (n-major)
        const float* __restrict__ dinv,
        unsigned short* __restrict__ hs2, int N)
{
    __shared__ unsigned short sW1[128 * W1T_ST];
    __shared__ unsigned short sW2[64 * W2T_ST];
    __shared__ unsigned short sA[TILE * A_ST];
    __shared__ unsigned short sX[TILE * X1_ST];
    __shared__ float sdv[TILE];

    const int tid  = threadIdx.x;
    const int row0 = blockIdx.x * TILE;
    const int lane = tid & 63;
    const int wv   = tid >> 6;        // wave 0..3
    const int l16  = lane & 15;
    const int quad = lane >> 4;       // 0..3

    // ---- stage W1t (128 rows x 8 chunks of 8 bf16) ----
    for (int i = tid; i < 128 * 8; i += 256) {
        int r = i >> 3, c = i & 7;
        *(uint4*)&sW1[r * W1T_ST + c * 8] = *(const uint4*)&W1t[r * 64 + c * 8];
    }
    // ---- stage W2t (64 rows x 16 chunks) ----
    for (int i = tid; i < 64 * 16; i += 256) {
        int r = i >> 4, c = i & 15;
        *(uint4*)&sW2[r * W2T_ST + c * 8] = *(const uint4*)&W2t[r * 128 + c * 8];
    }
    // ---- stage A tile (32 rows x 8 chunks) ----
    for (int i = tid; i < TILE * 8; i += 256) {
        int r = i >> 3, c = i & 7;
        int gr = row0 + r;
        uint4 v = make_uint4(0u, 0u, 0u, 0u);
        if (gr < N) v = *(const uint4*)&agg1[(size_t)gr * 64 + c * 8];
        *(uint4*)&sA[r * A_ST + c * 8] = v;
    }
    if (tid < TILE) {
        int gr = row0 + tid;
        sdv[tid] = (gr < N) ? dinv[gr] : 0.0f;
    }
    __syncthreads();

    // ---- phase 1: 32x128 output, 16 MFMA tiles, 4 per wave ----
    {
        const int mt  = wv & 1;
        const int ntb = (wv >> 1) * 4;
        f32x4 acc[4];
#pragma unroll
        for (int t = 0; t < 4; ++t) acc[t] = (f32x4)0.0f;

#pragma unroll
        for (int k0 = 0; k0 < 64; k0 += 32) {
            bf16x8 af = *(const bf16x8*)&sA[(mt * 16 + l16) * A_ST + k0 + quad * 8];
#pragma unroll
            for (int t = 0; t < 4; ++t) {
                bf16x8 bf = *(const bf16x8*)&sW1[((ntb + t) * 16 + l16) * W1T_ST + k0 + quad * 8];
                acc[t] = __builtin_amdgcn_mfma_f32_16x16x32_bf16(af, bf, acc[t], 0, 0, 0);
            }
        }

#pragma unroll
        for (int t = 0; t < 4; ++t) {
            int col = (ntb + t) * 16 + l16;
            float bb = b1[col];
#pragma unroll
            for (int r = 0; r < 4; ++r) {
                int lr = mt * 16 + quad * 4 + r;
                float o = fmaxf(acc[t][r] * sdv[lr] + bb, 0.0f);
                sX[lr * X1_ST + col] = f32_to_bf16(o);
            }
        }
    }
    __syncthreads();

    // ---- phase 2: 32x64 output, 8 MFMA tiles, 2 per wave ----
    {
        const int mt  = wv & 1;
        const int ntb = (wv >> 1) * 2;
        f32x4 acc[2];
#pragma unroll
        for (int t = 0; t < 2; ++t) acc[t] = (f32x4)0.0f;

#pragma unroll
        for (int k0 = 0; k0 < 128; k0 += 32) {
            bf16x8 af = *(const bf16x8*)&sX[(mt * 16 + l16) * X1_ST + k0 + quad * 8];
#pragma unroll
            for (int t = 0; t < 2; ++t) {
                bf16x8 bf = *(const bf16x8*)&sW2[((ntb + t) * 16 + l16) * W2T_ST + k0 + quad * 8];
                acc[t] = __builtin_amdgcn_mfma_f32_16x16x32_bf16(af, bf, acc[t], 0, 0, 0);
            }
        }

#pragma unroll
        for (int t = 0; t < 2; ++t) {
            int col = (ntb + t) * 16 + l16;
#pragma unroll
            for (int r = 0; r < 4; ++r) {
                int lr = mt * 16 + quad * 4 + r;
                int gr = row0 + lr;
                if (gr < N)
                    hs2[(size_t)gr * 64 + col] = f32_to_bf16(acc[t][r] * sdv[lr]);
            }
        }
    }
}

static inline size_t align_up(size_t x, size_t a) { return (x + a - 1) / a * a; }

extern "C" void kernel_launch(void* const* d_in, const int* in_sizes, int n_in,
                              void* d_out, int out_size, void* d_ws, size_t ws_size,
                              hipStream_t stream) {
    const float* z    = (const float*)d_in[0];   // [N,64]
    const int*   eidx = (const int*)d_in[1];     // [2,E]: src row then dst row
    const float* W1   = (const float*)d_in[2];   // [64,128]
    const float* b1   = (const float*)d_in[3];   // [128]
    const float* W2   = (const float*)d_in[4];   // [128,64]
    const float* b2   = (const float*)d_in[5];   // [64]
    float* out = (float*)d_out;                  // [N,64]

    const int N = in_sizes[0] / 64;
    const int E = in_sizes[1] / 2;
    const int* src = eidx;
    const int* dst = eidx + E;
    const int NB = (N + NPB - 1) >> BSHIFT;      // 391 for N=100000

    // Workspace: small arrays | W1t | W2t | csr | bufA | bufB | bufC
    // u (bf16) in bufA; agg1 (bf16) in bufB; hs2 (bf16) overwrites u in bufA
    // (u fully consumed by aggregate PRE before gemm12 writes hs2);
    // esrc+edloc alias bufC (dead after build_csr).
    char* ws = (char*)d_ws;
    size_t off = 0;
    float* dinv    = (float*)(ws + off); off = align_up(off + (size_t)N * 4, 512);
    int*   rbeg    = (int*)  (ws + off); off = align_up(off + (size_t)N * 4, 512);
    int*   rend    = (int*)  (ws + off); off = align_up(off + (size_t)N * 4, 512);
    int*   bcursor = (int*)  (ws + off); off = align_up(off + (size_t)NBMAX * 4, 512);
    unsigned short* W1t = (unsigned short*)(ws + off); off = align_up(off + 8192 * 2, 512);
    unsigned short* W2t = (unsigned short*)(ws + off); off = align_up(off + 8192 * 2, 512);
    int*   csr     = (int*)  (ws + off); off = align_up(off + (size_t)NB * CAP * 4, 512);
    float* bufA    = (float*)(ws + off); off = align_up(off + (size_t)N * 64 * 4, 512);
    float* bufB    = (float*)(ws + off); off = align_up(off + (size_t)N * 64 * 4, 512);
    float* bufC    = (float*)(ws + off); off = align_up(off + (size_t)N * 128 * 4, 512);
    (void)ws_size;

    unsigned short* u    = (unsigned short*)bufA;   // bf16 z*dinv
    unsigned short* agg1 = (unsigned short*)bufB;   // bf16 aggregated u
    unsigned short* hs2  = (unsigned short*)bufA;   // bf16 layer-2 pre-aggregate
    int*            esrc  = (int*)bufC;
    unsigned char*  edloc = (unsigned char*)((char*)bufC + (size_t)NB * CAP * 4);

    // ---- prep (cursor zero + W transpose/convert) ----
    prep<<<32, 256, 0, stream>>>(W1, W2, W1t, W2t, bcursor, NB);

    // ---- CSR build (+ fused dinv & u-scale) ----
    bin_edges<<<(E + CH - 1) / CH, 256, 0, stream>>>(src, dst, bcursor, esrc, edloc, E, NB);
    build_csr<<<NB, 256, 0, stream>>>(esrc, edloc, bcursor, z, dinv, rbeg, rend, csr, u, N);

    // ---- layer 1 aggregate (pre-GEMM, uniform-32 masked gather) ----
    aggregate64_bf16<false><<<(N + 3) / 4, 256, 0, stream>>>(u, rbeg, rend, csr, dinv, nullptr, agg1, N);

    // ---- fused dual GEMM on MFMA (x1 never leaves LDS) ----
    gemm12_mfma<<<(N + TILE - 1) / TILE, 256, 0, stream>>>(agg1, W1t, b1, W2t, dinv, hs2, N);

    // ---- layer 2 aggregate (post-GEMM, uniform-32 gather, fp32 NT out) ----
    aggregate64_bf16<true><<<(N + 3) / 4, 256, 0, stream>>>(hs2, rbeg, rend, csr, dinv, b2, out, N);
}

// Round 3
// 266.091 us; speedup vs baseline: 1.2642x; 1.2642x over previous
//
#include <hip/hip_runtime.h>
#include <hip/hip_bf16.h>

// GCN 2-layer forward. Pipeline (6 kernels):
//   prep          : zero bucket cursors + W1,W2 -> bf16 transposed + ZERO ROW
//   bin_edges     : edges -> bucket-strided esrc (int) + edloc (uchar local dst)
//   build_csr     : per-bucket LDS histogram/prefix -> dinv, rbeg/rend, csr,
//                   AND u = bf16(z * dinv[:,None])
//   aggregate PRE : agg1_d = bf16(u_d + sum u_s)    (16-wide, zero-row tail)
//   gemm12_mfma   : x1 = relu(dinv*(agg1@W1)+b1) in LDS (bf16);
//                   hs2 = bf16(dinv*(x1@W2))       (both GEMMs on MFMA)
//   aggregate POST: out_d = dinv_d*(hs2_d + sum hs2_s) + b2  (fp32 NT store)
//
// Round-3 notes (lessons from r1/r2 regressions):
//  - r1: fusing aggregate into GEMM regressed (barrier idling, LDS occupancy cap).
//  - r2: clamping the CSR *address* before the load (csr[idx<end?idx:last])
//    broke the contiguous scalar-load pattern -> 32 serialized s_cselect+s_load
//    chains + 2x duplicated random gathers. 77us vs 43.8us.
//  - r3: masking moved AFTER the load, onto the VALUE: indices loaded
//    contiguously (merged scalar loads, round-0 codegen), then
//    s[j] = (e+j<end) ? s[j] : N where row N is a dedicated ZERO row
//    (L1-hot 128B, adds exact 0.0). Pure 16-wide batches: dependent waits/row
//    ~3.7 -> ~1.4 at round-0's VGPR budget.

#define WAVE 64
#define BSHIFT 8
#define NPB 256              // nodes per bucket
#define CAP 5120             // max edges per bucket (mean 4096, +16 sigma)
#define CH 4096              // edges per WG in bin_edges
#define NBMAX 512

typedef __attribute__((ext_vector_type(8))) short bf16x8;
typedef __attribute__((ext_vector_type(4))) float f32x4;

__device__ inline float bf16_to_f32(unsigned short h) {
    return __uint_as_float(((unsigned int)h) << 16);
}
__device__ inline unsigned short f32_to_bf16(float f) {
    unsigned int x = __float_as_uint(f);
    return (unsigned short)((x + 0x7FFFu + ((x >> 16) & 1u)) >> 16);   // RNE
}

// 16-wide gather with zero-row tail: acc += sum of bf16 rows hs[csr[e]][lane].
// Indices loaded contiguously (wave-uniform -> merged scalar loads), THEN the
// overhang is redirected to row `zrow` (a dedicated all-zero row, L1-hot).
// One vmcnt wait per 16 edges; no per-value masking needed.
__device__ inline float gather_rows16(const unsigned short* __restrict__ hs,
                                      const int* __restrict__ csr,
                                      int beg, int end, int lane, int zrow,
                                      float acc)
{
    for (int e = beg; e < end; e += 16) {
        int s[16];
#pragma unroll
        for (int j = 0; j < 16; ++j) s[j] = csr[e + j];   // contiguous, unconditional
#pragma unroll
        for (int j = 0; j < 16; ++j)
            s[j] = (e + j < end) ? s[j] : zrow;           // scalar cselect AFTER load
        float v[16];
#pragma unroll
        for (int j = 0; j < 16; ++j)
            v[j] = bf16_to_f32(hs[(size_t)s[j] * 64 + lane]);
        float t0 = ((v[0] + v[1]) + (v[2] + v[3])) + ((v[4] + v[5]) + (v[6] + v[7]));
        float t1 = ((v[8] + v[9]) + (v[10] + v[11])) + ((v[12] + v[13]) + (v[14] + v[15]));
        acc += t0 + t1;
    }
    return acc;
}

// ---------------- prep: zero cursors + W -> bf16 transposed + zero row ------
__global__ void prep(const float* __restrict__ W1, const float* __restrict__ W2,
                     unsigned short* __restrict__ W1t, unsigned short* __restrict__ W2t,
                     int* __restrict__ bcursor, int NB,
                     unsigned short* __restrict__ zr, int N)
{
    int i = blockIdx.x * blockDim.x + threadIdx.x;
    if (i < NB) bcursor[i] = 0;
    if (i < 64) zr[(size_t)N * 64 + i] = 0;   // zero row (gather tail target)
    if (i < 128 * 64) {          // W1t[n][k] = W1[k][n]  (W1 is [64][128])
        int n = i >> 6, k = i & 63;
        W1t[i] = f32_to_bf16(W1[k * 128 + n]);
    }
    if (i < 64 * 128) {          // W2t[n][k] = W2[k][n]  (W2 is [128][64])
        int n = i >> 7, k = i & 127;
        W2t[i] = f32_to_bf16(W2[k * 64 + n]);
    }
}

// ---------------- bin_edges: scatter edges into bucket-strided esrc/edloc ---
__global__ __launch_bounds__(256) void bin_edges(
        const int* __restrict__ src, const int* __restrict__ dst,
        int* __restrict__ bcursor, int* __restrict__ esrc,
        unsigned char* __restrict__ edloc, int E, int NB)
{
    __shared__ int hist[NBMAX];
    __shared__ int cur[NBMAX];
    const int t  = threadIdx.x;
    const int e0 = blockIdx.x * CH;

    for (int b = t; b < NB; b += 256) hist[b] = 0;
    __syncthreads();

#pragma unroll
    for (int j = 0; j < CH / 256; ++j) {
        int e = e0 + j * 256 + t;
        if (e < E) atomicAdd(&hist[dst[e] >> BSHIFT], 1);
    }
    __syncthreads();

    for (int b = t; b < NB; b += 256) {
        int c = hist[b];
        cur[b] = (c > 0) ? atomicAdd(&bcursor[b], c) : 0;
    }
    __syncthreads();

#pragma unroll
    for (int j = 0; j < CH / 256; ++j) {
        int e = e0 + j * 256 + t;
        if (e < E) {
            int s = __builtin_nontemporal_load(&src[e]);   // read once -> NT
            int d = dst[e];                                 // L1/L2-warm from pass 1
            int b = d >> BSHIFT;
            int pos = atomicAdd(&cur[b], 1);
            size_t idx = (size_t)b * CAP + pos;
            esrc[idx]  = s;
            edloc[idx] = (unsigned char)(d & (NPB - 1));
        }
    }
}

// ---------------- build_csr + fused u = bf16(z*dinv) ----------------
__global__ __launch_bounds__(256) void build_csr(
        const int* __restrict__ esrc, const unsigned char* __restrict__ edloc,
        const int* __restrict__ bcursor,
        const float* __restrict__ z, float* __restrict__ dinv,
        int* __restrict__ rbeg, int* __restrict__ rend,
        int* __restrict__ csr, unsigned short* __restrict__ u, int N)
{
    __shared__ int   h[NPB];
    __shared__ int   tmp[NPB];
    __shared__ float sdv[NPB];
    const int t   = threadIdx.x;
    const int b   = blockIdx.x;
    const int n0  = b << BSHIFT;
    const int cnt = bcursor[b];
    const size_t base = (size_t)b * CAP;

    h[t] = 0;
    __syncthreads();

    for (int i = t; i < cnt; i += 256)
        atomicAdd(&h[edloc[base + i]], 1);
    __syncthreads();

    int deg = h[t];
    tmp[t] = deg;
    __syncthreads();
    for (int off = 1; off < 256; off <<= 1) {
        int x = (t >= off) ? tmp[t - off] : 0;
        __syncthreads();
        tmp[t] += x;
        __syncthreads();
    }
    int st = tmp[t] - deg;

    int node = n0 + t;
    float di = rsqrtf((float)deg + 1.0f);
    sdv[t] = di;
    if (node < N) {
        dinv[node] = di;
        rbeg[node] = (int)base + st;
        rend[node] = (int)base + st + deg;
    }
    h[t] = st;
    __syncthreads();   // covers h-cursor reset and sdv visibility

    for (int i = t; i < cnt; i += 256) {
        int dl = edloc[base + i];
        int p = atomicAdd(&h[dl], 1);
        csr[base + p] = __builtin_nontemporal_load(&esrc[base + i]);
    }

    // fused scale: u rows for this bucket (16 threads per row, float4 reads)
    const int nloc = (N - n0 < NPB) ? (N - n0) : NPB;
    for (int i = t; i < nloc * 16; i += 256) {
        int r = i >> 4, kq = i & 15;
        float d2 = sdv[r];
        const f32x4* zr = (const f32x4*)(z + (size_t)(n0 + r) * 64);
        f32x4 v = __builtin_nontemporal_load(zr + kq);     // z read once -> NT
        ushort4 o;
        o.x = f32_to_bf16(v[0] * d2);
        o.y = f32_to_bf16(v[1] * d2);
        o.z = f32_to_bf16(v[2] * d2);
        o.w = f32_to_bf16(v[3] * d2);
        ((ushort4*)(u + (size_t)(n0 + r) * 64))[kq] = o;
    }
}

// ---------------- aggregate (F=64, bf16 rows), one wave per node -----------
// PRE  (POST=false): out = bf16(hs_d + sum hs_s)        -> ushort* (normal store:
//                    agg1 is re-read linearly by the GEMM right after, keep in L2)
// POST (POST=true):  out = dinv_d*(hs_d + sum hs_s) + b -> float* (NT store:
//                    out never re-read; protect L2 ways for the gather table)
template<bool POST>
__global__ __launch_bounds__(256) void aggregate64_bf16(
        const unsigned short* __restrict__ hs, const int* __restrict__ rbeg,
        const int* __restrict__ rend, const int* __restrict__ csr,
        const float* __restrict__ dinv, const float* __restrict__ b,
        void* __restrict__ out_, int N)
{
    int node = (int)((blockIdx.x * (size_t)blockDim.x + threadIdx.x) >> 6);
    int lane = threadIdx.x & 63;
    if (node >= N) return;
    node = __builtin_amdgcn_readfirstlane(node);   // wave-uniform -> scalar loads

    const int beg = rbeg[node];
    const int end = rend[node];

    float acc = bf16_to_f32(hs[(size_t)node * 64 + lane]);   // self-loop term
    acc = gather_rows16(hs, csr, beg, end, lane, N, acc);    // row N == zero row

    if (POST) {
        float o = dinv[node] * acc + b[lane];
        __builtin_nontemporal_store(o, &((float*)out_)[(size_t)node * 64 + lane]);
    } else {
        ((unsigned short*)out_)[(size_t)node * 64 + lane] = f32_to_bf16(acc);
    }
}

// ---------------- fused dual GEMM on MFMA ----------------
// Per 32-row tile:
//   phase 1: x1 = relu(dinv*(agg1@W1)+b1)  -> LDS bf16 (A-operand layout)
//   phase 2: hs2 = bf16(dinv*(x1@W2))      -> global (normal store; gather table)
// mfma_f32_16x16x32_bf16 layouts (HW-verified, learn_hip m89/m91/m120):
//   A: lane holds A[m=lane&15][k = (lane>>4)*8 + j]  (8 contiguous bf16)
//   B: lane holds B[k=(lane>>4)*8+j][n=lane&15]  -> stage W transposed Wt[n][k]
//   C/D: col = lane&15, row = (lane>>4)*4 + reg
// LDS ~49.3 KB -> 3 WGs/CU. Padded strides (72/136 ushorts) keep reads ~2-way.
#define TILE 32
#define W1T_ST 72
#define W2T_ST 136
#define A_ST   72
#define X1_ST  136

__global__ __launch_bounds__(256) void gemm12_mfma(
        const unsigned short* __restrict__ agg1,   // bf16 [N][64]
        const unsigned short* __restrict__ W1t,    // bf16 [128][64]  (n-major)
        const float* __restrict__ b1,              // [128]
        const unsigned short* __restrict__ W2t,    // bf16 [64][128]  (n-major)
        const float* __restrict__ dinv,
        unsigned short* __restrict__ hs2, int N)
{
    __shared__ unsigned short sW1[128 * W1T_ST];
    __shared__ unsigned short sW2[64 * W2T_ST];
    __shared__ unsigned short sA[TILE * A_ST];
    __shared__ unsigned short sX[TILE * X1_ST];
    __shared__ float sdv[TILE];

    const int tid  = threadIdx.x;
    const int row0 = blockIdx.x * TILE;
    const int lane = tid & 63;
    const int wv   = tid >> 6;        // wave 0..3
    const int l16  = lane & 15;
    const int quad = lane >> 4;       // 0..3

    // ---- stage W1t (128 rows x 8 chunks of 8 bf16) ----
    for (int i = tid; i < 128 * 8; i += 256) {
        int r = i >> 3, c = i & 7;
        *(uint4*)&sW1[r * W1T_ST + c * 8] = *(const uint4*)&W1t[r * 64 + c * 8];
    }
    // ---- stage W2t (64 rows x 16 chunks) ----
    for (int i = tid; i < 64 * 16; i += 256) {
        int r = i >> 4, c = i & 15;
        *(uint4*)&sW2[r * W2T_ST + c * 8] = *(const uint4*)&W2t[r * 128 + c * 8];
    }
    // ---- stage A tile (32 rows x 8 chunks) ----
    for (int i = tid; i < TILE * 8; i += 256) {
        int r = i >> 3, c = i & 7;
        int gr = row0 + r;
        uint4 v = make_uint4(0u, 0u, 0u, 0u);
        if (gr < N) v = *(const uint4*)&agg1[(size_t)gr * 64 + c * 8];
        *(uint4*)&sA[r * A_ST + c * 8] = v;
    }
    if (tid < TILE) {
        int gr = row0 + tid;
        sdv[tid] = (gr < N) ? dinv[gr] : 0.0f;
    }
    __syncthreads();

    // ---- phase 1: 32x128 output, 16 MFMA tiles, 4 per wave ----
    {
        const int mt  = wv & 1;
        const int ntb = (wv >> 1) * 4;
        f32x4 acc[4];
#pragma unroll
        for (int t = 0; t < 4; ++t) acc[t] = (f32x4)0.0f;

#pragma unroll
        for (int k0 = 0; k0 < 64; k0 += 32) {
            bf16x8 af = *(const bf16x8*)&sA[(mt * 16 + l16) * A_ST + k0 + quad * 8];
#pragma unroll
            for (int t = 0; t < 4; ++t) {
                bf16x8 bf = *(const bf16x8*)&sW1[((ntb + t) * 16 + l16) * W1T_ST + k0 + quad * 8];
                acc[t] = __builtin_amdgcn_mfma_f32_16x16x32_bf16(af, bf, acc[t], 0, 0, 0);
            }
        }

#pragma unroll
        for (int t = 0; t < 4; ++t) {
            int col = (ntb + t) * 16 + l16;
            float bb = b1[col];
#pragma unroll
            for (int r = 0; r < 4; ++r) {
                int lr = mt * 16 + quad * 4 + r;
                float o = fmaxf(acc[t][r] * sdv[lr] + bb, 0.0f);
                sX[lr * X1_ST + col] = f32_to_bf16(o);
            }
        }
    }
    __syncthreads();

    // ---- phase 2: 32x64 output, 8 MFMA tiles, 2 per wave ----
    {
        const int mt  = wv & 1;
        const int ntb = (wv >> 1) * 2;
        f32x4 acc[2];
#pragma unroll
        for (int t = 0; t < 2; ++t) acc[t] = (f32x4)0.0f;

#pragma unroll
        for (int k0 = 0; k0 < 128; k0 += 32) {
            bf16x8 af = *(const bf16x8*)&sX[(mt * 16 + l16) * X1_ST + k0 + quad * 8];
#pragma unroll
            for (int t = 0; t < 2; ++t) {
                bf16x8 bf = *(const bf16x8*)&sW2[((ntb + t) * 16 + l16) * W2T_ST + k0 + quad * 8];
                acc[t] = __builtin_amdgcn_mfma_f32_16x16x32_bf16(af, bf, acc[t], 0, 0, 0);
            }
        }

#pragma unroll
        for (int t = 0; t < 2; ++t) {
            int col = (ntb + t) * 16 + l16;
#pragma unroll
            for (int r = 0; r < 4; ++r) {
                int lr = mt * 16 + quad * 4 + r;
                int gr = row0 + lr;
                if (gr < N)
                    hs2[(size_t)gr * 64 + col] = f32_to_bf16(acc[t][r] * sdv[lr]);
            }
        }
    }
}

static inline size_t align_up(size_t x, size_t a) { return (x + a - 1) / a * a; }

extern "C" void kernel_launch(void* const* d_in, const int* in_sizes, int n_in,
                              void* d_out, int out_size, void* d_ws, size_t ws_size,
                              hipStream_t stream) {
    const float* z    = (const float*)d_in[0];   // [N,64]
    const int*   eidx = (const int*)d_in[1];     // [2,E]: src row then dst row
    const float* W1   = (const float*)d_in[2];   // [64,128]
    const float* b1   = (const float*)d_in[3];   // [128]
    const float* W2   = (const float*)d_in[4];   // [128,64]
    const float* b2   = (const float*)d_in[5];   // [64]
    float* out = (float*)d_out;                  // [N,64]

    const int N = in_sizes[0] / 64;
    const int E = in_sizes[1] / 2;
    const int* src = eidx;
    const int* dst = eidx + E;
    const int NB = (N + NPB - 1) >> BSHIFT;      // 391 for N=100000

    // Workspace: small arrays | W1t | W2t | csr | bufA | bufB | bufC
    // u (bf16, N+1 rows incl. zero row) in bufA; agg1 (bf16) in bufB;
    // hs2 (bf16) overwrites u rows 0..N-1 in bufA -- row N (zero) survives
    // as the POST gather's tail target. esrc+edloc alias bufC.
    char* ws = (char*)d_ws;
    size_t off = 0;
    float* dinv    = (float*)(ws + off); off = align_up(off + (size_t)N * 4, 512);
    int*   rbeg    = (int*)  (ws + off); off = align_up(off + (size_t)N * 4, 512);
    int*   rend    = (int*)  (ws + off); off = align_up(off + (size_t)N * 4, 512);
    int*   bcursor = (int*)  (ws + off); off = align_up(off + (size_t)NBMAX * 4, 512);
    unsigned short* W1t = (unsigned short*)(ws + off); off = align_up(off + 8192 * 2, 512);
    unsigned short* W2t = (unsigned short*)(ws + off); off = align_up(off + 8192 * 2, 512);
    int*   csr     = (int*)  (ws + off); off = align_up(off + (size_t)NB * CAP * 4, 512);
    float* bufA    = (float*)(ws + off); off = align_up(off + (size_t)N * 64 * 4, 512);
    float* bufB    = (float*)(ws + off); off = align_up(off + (size_t)N * 64 * 4, 512);
    float* bufC    = (float*)(ws + off); off = align_up(off + (size_t)N * 128 * 4, 512);
    (void)ws_size;

    unsigned short* u    = (unsigned short*)bufA;   // bf16 z*dinv, rows 0..N (N = zero)
    unsigned short* agg1 = (unsigned short*)bufB;   // bf16 aggregated u
    unsigned short* hs2  = (unsigned short*)bufA;   // bf16 layer-2 pre-aggregate
    int*            esrc  = (int*)bufC;
    unsigned char*  edloc = (unsigned char*)((char*)bufC + (size_t)NB * CAP * 4);

    // ---- prep (cursor zero + W transpose/convert + zero row of u) ----
    prep<<<32, 256, 0, stream>>>(W1, W2, W1t, W2t, bcursor, NB, u, N);

    // ---- CSR build (+ fused dinv & u-scale) ----
    bin_edges<<<(E + CH - 1) / CH, 256, 0, stream>>>(src, dst, bcursor, esrc, edloc, E, NB);
    build_csr<<<NB, 256, 0, stream>>>(esrc, edloc, bcursor, z, dinv, rbeg, rend, csr, u, N);

    // ---- layer 1 aggregate (pre-GEMM, 16-wide zero-row-tail gather) ----
    aggregate64_bf16<false><<<(N + 3) / 4, 256, 0, stream>>>(u, rbeg, rend, csr, dinv, nullptr, agg1, N);

    // ---- fused dual GEMM on MFMA (x1 never leaves LDS) ----
    gemm12_mfma<<<(N + TILE - 1) / TILE, 256, 0, stream>>>(agg1, W1t, b1, W2t, dinv, hs2, N);

    // ---- layer 2 aggregate (post-GEMM, 16-wide zero-row-tail gather, NT out) ----
    aggregate64_bf16<true><<<(N + 3) / 4, 256, 0, stream>>>(hs2, rbeg, rend, csr, dinv, b2, out, N);
}

// Round 4
// 236.883 us; speedup vs baseline: 1.4201x; 1.1233x over previous
//
#include <hip/hip_runtime.h>
#include <hip/hip_bf16.h>

// GCN 2-layer forward. Pipeline (6 kernels):
//   prep          : zero bucket cursors + W1,W2 -> bf16 transposed + ZERO ROW
//   bin_edges     : edges -> bucket-strided int2 (src,dst)  [r0 form: single
//                   8B scatter store; r1's esrc/edloc split caused 49MB write
//                   amplification -> 58.6us, reverted]
//   build_csr     : per-bucket LDS histogram/prefix -> dinv, rbeg/rend, csr,
//                   AND u = bf16(z * dinv[:,None])
//   aggregate PRE : agg1_d = bf16(u_d + sum u_s)   (16-wide zero-row gather,
//                   NT store: agg1 read once sequentially by gemm; protect L2)
//   gemm12_mfma   : x1 = relu(dinv*(agg1@W1)+b1) in LDS (bf16);
//                   hs2 = bf16(dinv*(x1@W2))      (normal store: POST's table)
//   aggregate POST: out_d = dinv_d*(hs2_d + sum hs2_s) + b2  (fp32 NT store)
//
// Evidence log:
//  - r1: aggregate+GEMM fusion regressed (barrier idling, LDS occupancy cap).
//  - r2: address-clamped gather broke merged scalar index loads (77us).
//  - r3: value-masked zero-row gather ~neutral vs r0 (MLP was already 16-wide;
//    aggregate is random-fetch-throughput bound at ~2.1-2.8 TB/s, FETCH 92MB
//    ~= 8 XCDs x 55%-miss stream of the 12.8MB table -> structural at bf16).
//  - r3 counters: bin_edges esrc/edloc split = write-amplified (49MB HBM write
//    for 8MB logical, 845GB/s scattered-write ceiling) -> revert to int2.

#define WAVE 64
#define BSHIFT 8
#define NPB 256              // nodes per bucket
#define CAP 5120             // max edges per bucket (mean 4096, +16 sigma)
#define CH 4096              // edges per WG in bin_edges
#define NBMAX 512

typedef __attribute__((ext_vector_type(8))) short bf16x8;
typedef __attribute__((ext_vector_type(4))) float f32x4;

__device__ inline float bf16_to_f32(unsigned short h) {
    return __uint_as_float(((unsigned int)h) << 16);
}
__device__ inline unsigned short f32_to_bf16(float f) {
    unsigned int x = __float_as_uint(f);
    return (unsigned short)((x + 0x7FFFu + ((x >> 16) & 1u)) >> 16);   // RNE
}

// 16-wide gather with zero-row tail: acc += sum of bf16 rows hs[csr[e]][lane].
// Indices loaded contiguously (wave-uniform -> merged scalar loads), THEN the
// overhang is redirected to row `zrow` (a dedicated all-zero row, L1-hot).
__device__ inline float gather_rows16(const unsigned short* __restrict__ hs,
                                      const int* __restrict__ csr,
                                      int beg, int end, int lane, int zrow,
                                      float acc)
{
    for (int e = beg; e < end; e += 16) {
        int s[16];
#pragma unroll
        for (int j = 0; j < 16; ++j) s[j] = csr[e + j];   // contiguous, unconditional
#pragma unroll
        for (int j = 0; j < 16; ++j)
            s[j] = (e + j < end) ? s[j] : zrow;           // scalar cselect AFTER load
        float v[16];
#pragma unroll
        for (int j = 0; j < 16; ++j)
            v[j] = bf16_to_f32(hs[(size_t)s[j] * 64 + lane]);
        float t0 = ((v[0] + v[1]) + (v[2] + v[3])) + ((v[4] + v[5]) + (v[6] + v[7]));
        float t1 = ((v[8] + v[9]) + (v[10] + v[11])) + ((v[12] + v[13]) + (v[14] + v[15]));
        acc += t0 + t1;
    }
    return acc;
}

// ---------------- prep: zero cursors + W -> bf16 transposed + zero row ------
__global__ void prep(const float* __restrict__ W1, const float* __restrict__ W2,
                     unsigned short* __restrict__ W1t, unsigned short* __restrict__ W2t,
                     int* __restrict__ bcursor, int NB,
                     unsigned short* __restrict__ zr, int N)
{
    int i = blockIdx.x * blockDim.x + threadIdx.x;
    if (i < NB) bcursor[i] = 0;
    if (i < 64) zr[(size_t)N * 64 + i] = 0;   // zero row (gather tail target)
    if (i < 128 * 64) {          // W1t[n][k] = W1[k][n]  (W1 is [64][128])
        int n = i >> 6, k = i & 63;
        W1t[i] = f32_to_bf16(W1[k * 128 + n]);
    }
    if (i < 64 * 128) {          // W2t[n][k] = W2[k][n]  (W2 is [128][64])
        int n = i >> 7, k = i & 127;
        W2t[i] = f32_to_bf16(W2[k * 64 + n]);
    }
}

// ---------------- bin_edges: scatter edges into bucket-strided ebuf ---------
// r0 form: ONE int2 store per edge. Per (block,bucket) runs are ~10 edges =
// 84B -> ~1.3 dirty lines; write traffic ~logical size, not amplified.
__global__ __launch_bounds__(256) void bin_edges(
        const int* __restrict__ src, const int* __restrict__ dst,
        int* __restrict__ bcursor, int2* __restrict__ ebuf, int E, int NB)
{
    __shared__ int hist[NBMAX];
    __shared__ int cur[NBMAX];
    const int t  = threadIdx.x;
    const int e0 = blockIdx.x * CH;

    for (int b = t; b < NB; b += 256) hist[b] = 0;
    __syncthreads();

#pragma unroll
    for (int j = 0; j < CH / 256; ++j) {
        int e = e0 + j * 256 + t;
        if (e < E) atomicAdd(&hist[dst[e] >> BSHIFT], 1);
    }
    __syncthreads();

    for (int b = t; b < NB; b += 256) {
        int c = hist[b];
        cur[b] = (c > 0) ? atomicAdd(&bcursor[b], c) : 0;
    }
    __syncthreads();

#pragma unroll
    for (int j = 0; j < CH / 256; ++j) {
        int e = e0 + j * 256 + t;
        if (e < E) {
            int s = src[e], d = dst[e];
            int b = d >> BSHIFT;
            int pos = atomicAdd(&cur[b], 1);
            ebuf[(size_t)b * CAP + pos] = make_int2(s, d);
        }
    }
}

// ---------------- build_csr + fused u = bf16(z*dinv) (r0 form) --------------
__global__ __launch_bounds__(256) void build_csr(
        const int2* __restrict__ ebuf, const int* __restrict__ bcursor,
        const float* __restrict__ z, float* __restrict__ dinv,
        int* __restrict__ rbeg, int* __restrict__ rend,
        int* __restrict__ csr, unsigned short* __restrict__ u, int N)
{
    __shared__ int   h[NPB];
    __shared__ int   tmp[NPB];
    __shared__ float sdv[NPB];
    const int t   = threadIdx.x;
    const int b   = blockIdx.x;
    const int n0  = b << BSHIFT;
    const int cnt = bcursor[b];
    const size_t base = (size_t)b * CAP;

    h[t] = 0;
    __syncthreads();

    for (int i = t; i < cnt; i += 256)
        atomicAdd(&h[ebuf[base + i].y - n0], 1);
    __syncthreads();

    int deg = h[t];
    tmp[t] = deg;
    __syncthreads();
    for (int off = 1; off < 256; off <<= 1) {
        int x = (t >= off) ? tmp[t - off] : 0;
        __syncthreads();
        tmp[t] += x;
        __syncthreads();
    }
    int st = tmp[t] - deg;

    int node = n0 + t;
    float di = rsqrtf((float)deg + 1.0f);
    sdv[t] = di;
    if (node < N) {
        dinv[node] = di;
        rbeg[node] = (int)base + st;
        rend[node] = (int)base + st + deg;
    }
    h[t] = st;
    __syncthreads();   // covers h-cursor reset and sdv visibility

    for (int i = t; i < cnt; i += 256) {
        int2 e = ebuf[base + i];
        int p = atomicAdd(&h[e.y - n0], 1);
        csr[base + p] = e.x;
    }

    // fused scale: u rows for this bucket (16 threads per row, float4 reads)
    const int nloc = (N - n0 < NPB) ? (N - n0) : NPB;
    for (int i = t; i < nloc * 16; i += 256) {
        int r = i >> 4, kq = i & 15;
        float d2 = sdv[r];
        float4 v = ((const float4*)(z + (size_t)(n0 + r) * 64))[kq];
        ushort4 o;
        o.x = f32_to_bf16(v.x * d2);
        o.y = f32_to_bf16(v.y * d2);
        o.z = f32_to_bf16(v.z * d2);
        o.w = f32_to_bf16(v.w * d2);
        ((ushort4*)(u + (size_t)(n0 + r) * 64))[kq] = o;
    }
}

// ---------------- aggregate (F=64, bf16 rows), one wave per node -----------
// PRE  (POST=false): out = bf16(hs_d + sum hs_s)        -> ushort* NT store
//                    (agg1 read ONCE sequentially by gemm; keep L2 for gather)
// POST (POST=true):  out = dinv_d*(hs_d + sum hs_s) + b -> float* NT store
//                    (out never re-read)
template<bool POST>
__global__ __launch_bounds__(256) void aggregate64_bf16(
        const unsigned short* __restrict__ hs, const int* __restrict__ rbeg,
        const int* __restrict__ rend, const int* __restrict__ csr,
        const float* __restrict__ dinv, const float* __restrict__ b,
        void* __restrict__ out_, int N)
{
    int node = (int)((blockIdx.x * (size_t)blockDim.x + threadIdx.x) >> 6);
    int lane = threadIdx.x & 63;
    if (node >= N) return;
    node = __builtin_amdgcn_readfirstlane(node);   // wave-uniform -> scalar loads

    const int beg = rbeg[node];
    const int end = rend[node];

    float acc = bf16_to_f32(hs[(size_t)node * 64 + lane]);   // self-loop term
    acc = gather_rows16(hs, csr, beg, end, lane, N, acc);    // row N == zero row

    if (POST) {
        float o = dinv[node] * acc + b[lane];
        __builtin_nontemporal_store(o, &((float*)out_)[(size_t)node * 64 + lane]);
    } else {
        __builtin_nontemporal_store(f32_to_bf16(acc),
            &((unsigned short*)out_)[(size_t)node * 64 + lane]);
    }
}

// ---------------- fused dual GEMM on MFMA ----------------
// Per 32-row tile:
//   phase 1: x1 = relu(dinv*(agg1@W1)+b1)  -> LDS bf16 (A-operand layout)
//   phase 2: hs2 = bf16(dinv*(x1@W2))      -> global (normal store; gather table)
// mfma_f32_16x16x32_bf16 layouts (HW-verified, learn_hip m89/m91/m120):
//   A: lane holds A[m=lane&15][k = (lane>>4)*8 + j]  (8 contiguous bf16)
//   B: lane holds B[k=(lane>>4)*8+j][n=lane&15]  -> stage W transposed Wt[n][k]
//   C/D: col = lane&15, row = (lane>>4)*4 + reg
// LDS ~49.3 KB -> 3 WGs/CU. Padded strides (72/136 ushorts) keep reads ~2-way.
#define TILE 32
#define W1T_ST 72
#define W2T_ST 136
#define A_ST   72
#define X1_ST  136

__global__ __launch_bounds__(256) void gemm12_mfma(
        const unsigned short* __restrict__ agg1,   // bf16 [N][64]
        const unsigned short* __restrict__ W1t,    // bf16 [128][64]  (n-major)
        const float* __restrict__ b1,              // [128]
        const unsigned short* __restrict__ W2t,    // bf16 [64][128]  (n-major)
        const float* __restrict__ dinv,
        unsigned short* __restrict__ hs2, int N)
{
    __shared__ unsigned short sW1[128 * W1T_ST];
    __shared__ unsigned short sW2[64 * W2T_ST];
    __shared__ unsigned short sA[TILE * A_ST];
    __shared__ unsigned short sX[TILE * X1_ST];
    __shared__ float sdv[TILE];

    const int tid  = threadIdx.x;
    const int row0 = blockIdx.x * TILE;
    const int lane = tid & 63;
    const int wv   = tid >> 6;        // wave 0..3
    const int l16  = lane & 15;
    const int quad = lane >> 4;       // 0..3

    // ---- stage W1t (128 rows x 8 chunks of 8 bf16) ----
    for (int i = tid; i < 128 * 8; i += 256) {
        int r = i >> 3, c = i & 7;
        *(uint4*)&sW1[r * W1T_ST + c * 8] = *(const uint4*)&W1t[r * 64 + c * 8];
    }
    // ---- stage W2t (64 rows x 16 chunks) ----
    for (int i = tid; i < 64 * 16; i += 256) {
        int r = i >> 4, c = i & 15;
        *(uint4*)&sW2[r * W2T_ST + c * 8] = *(const uint4*)&W2t[r * 128 + c * 8];
    }
    // ---- stage A tile (32 rows x 8 chunks) ----
    for (int i = tid; i < TILE * 8; i += 256) {
        int r = i >> 3, c = i & 7;
        int gr = row0 + r;
        uint4 v = make_uint4(0u, 0u, 0u, 0u);
        if (gr < N) v = *(const uint4*)&agg1[(size_t)gr * 64 + c * 8];
        *(uint4*)&sA[r * A_ST + c * 8] = v;
    }
    if (tid < TILE) {
        int gr = row0 + tid;
        sdv[tid] = (gr < N) ? dinv[gr] : 0.0f;
    }
    __syncthreads();

    // ---- phase 1: 32x128 output, 16 MFMA tiles, 4 per wave ----
    {
        const int mt  = wv & 1;
        const int ntb = (wv >> 1) * 4;
        f32x4 acc[4];
#pragma unroll
        for (int t = 0; t < 4; ++t) acc[t] = (f32x4)0.0f;

#pragma unroll
        for (int k0 = 0; k0 < 64; k0 += 32) {
            bf16x8 af = *(const bf16x8*)&sA[(mt * 16 + l16) * A_ST + k0 + quad * 8];
#pragma unroll
            for (int t = 0; t < 4; ++t) {
                bf16x8 bf = *(const bf16x8*)&sW1[((ntb + t) * 16 + l16) * W1T_ST + k0 + quad * 8];
                acc[t] = __builtin_amdgcn_mfma_f32_16x16x32_bf16(af, bf, acc[t], 0, 0, 0);
            }
        }

#pragma unroll
        for (int t = 0; t < 4; ++t) {
            int col = (ntb + t) * 16 + l16;
            float bb = b1[col];
#pragma unroll
            for (int r = 0; r < 4; ++r) {
                int lr = mt * 16 + quad * 4 + r;
                float o = fmaxf(acc[t][r] * sdv[lr] + bb, 0.0f);
                sX[lr * X1_ST + col] = f32_to_bf16(o);
            }
        }
    }
    __syncthreads();

    // ---- phase 2: 32x64 output, 8 MFMA tiles, 2 per wave ----
    {
        const int mt  = wv & 1;
        const int ntb = (wv >> 1) * 2;
        f32x4 acc[2];
#pragma unroll
        for (int t = 0; t < 2; ++t) acc[t] = (f32x4)0.0f;

#pragma unroll
        for (int k0 = 0; k0 < 128; k0 += 32) {
            bf16x8 af = *(const bf16x8*)&sX[(mt * 16 + l16) * X1_ST + k0 + quad * 8];
#pragma unroll
            for (int t = 0; t < 2; ++t) {
                bf16x8 bf = *(const bf16x8*)&sW2[((ntb + t) * 16 + l16) * W2T_ST + k0 + quad * 8];
                acc[t] = __builtin_amdgcn_mfma_f32_16x16x32_bf16(af, bf, acc[t], 0, 0, 0);
            }
        }

#pragma unroll
        for (int t = 0; t < 2; ++t) {
            int col = (ntb + t) * 16 + l16;
#pragma unroll
            for (int r = 0; r < 4; ++r) {
                int lr = mt * 16 + quad * 4 + r;
                int gr = row0 + lr;
                if (gr < N)
                    hs2[(size_t)gr * 64 + col] = f32_to_bf16(acc[t][r] * sdv[lr]);
            }
        }
    }
}

static inline size_t align_up(size_t x, size_t a) { return (x + a - 1) / a * a; }

extern "C" void kernel_launch(void* const* d_in, const int* in_sizes, int n_in,
                              void* d_out, int out_size, void* d_ws, size_t ws_size,
                              hipStream_t stream) {
    const float* z    = (const float*)d_in[0];   // [N,64]
    const int*   eidx = (const int*)d_in[1];     // [2,E]: src row then dst row
    const float* W1   = (const float*)d_in[2];   // [64,128]
    const float* b1   = (const float*)d_in[3];   // [128]
    const float* W2   = (const float*)d_in[4];   // [128,64]
    const float* b2   = (const float*)d_in[5];   // [64]
    float* out = (float*)d_out;                  // [N,64]

    const int N = in_sizes[0] / 64;
    const int E = in_sizes[1] / 2;
    const int* src = eidx;
    const int* dst = eidx + E;
    const int NB = (N + NPB - 1) >> BSHIFT;      // 391 for N=100000

    // Workspace: small arrays | W1t | W2t | csr | bufA | bufB | bufC
    // u (bf16, N+1 rows incl. zero row) in bufA; agg1 (bf16) in bufB;
    // hs2 (bf16) overwrites u rows 0..N-1 in bufA -- row N (zero) survives
    // as the POST gather's tail target. ebuf (int2) aliases bufC.
    char* ws = (char*)d_ws;
    size_t off = 0;
    float* dinv    = (float*)(ws + off); off = align_up(off + (size_t)N * 4, 512);
    int*   rbeg    = (int*)  (ws + off); off = align_up(off + (size_t)N * 4, 512);
    int*   rend    = (int*)  (ws + off); off = align_up(off + (size_t)N * 4, 512);
    int*   bcursor = (int*)  (ws + off); off = align_up(off + (size_t)NBMAX * 4, 512);
    unsigned short* W1t = (unsigned short*)(ws + off); off = align_up(off + 8192 * 2, 512);
    unsigned short* W2t = (unsigned short*)(ws + off); off = align_up(off + 8192 * 2, 512);
    int*   csr     = (int*)  (ws + off); off = align_up(off + (size_t)NB * CAP * 4, 512);
    float* bufA    = (float*)(ws + off); off = align_up(off + (size_t)N * 64 * 4, 512);
    float* bufB    = (float*)(ws + off); off = align_up(off + (size_t)N * 64 * 4, 512);
    float* bufC    = (float*)(ws + off); off = align_up(off + (size_t)N * 128 * 4, 512);
    (void)ws_size;

    unsigned short* u    = (unsigned short*)bufA;   // bf16 z*dinv, rows 0..N (N = zero)
    unsigned short* agg1 = (unsigned short*)bufB;   // bf16 aggregated u
    unsigned short* hs2  = (unsigned short*)bufA;   // bf16 layer-2 pre-aggregate
    int2*  ebuf    = (int2*)bufC;

    // ---- prep (cursor zero + W transpose/convert + zero row of u) ----
    prep<<<32, 256, 0, stream>>>(W1, W2, W1t, W2t, bcursor, NB, u, N);

    // ---- CSR build (+ fused dinv & u-scale) ----
    bin_edges<<<(E + CH - 1) / CH, 256, 0, stream>>>(src, dst, bcursor, ebuf, E, NB);
    build_csr<<<NB, 256, 0, stream>>>(ebuf, bcursor, z, dinv, rbeg, rend, csr, u, N);

    // ---- layer 1 aggregate (pre-GEMM, 16-wide zero-row-tail gather, NT out) ----
    aggregate64_bf16<false><<<(N + 3) / 4, 256, 0, stream>>>(u, rbeg, rend, csr, dinv, nullptr, agg1, N);

    // ---- fused dual GEMM on MFMA (x1 never leaves LDS) ----
    gemm12_mfma<<<(N + TILE - 1) / TILE, 256, 0, stream>>>(agg1, W1t, b1, W2t, dinv, hs2, N);

    // ---- layer 2 aggregate (post-GEMM, 16-wide zero-row-tail gather, NT out) ----
    aggregate64_bf16<true><<<(N + 3) / 4, 256, 0, stream>>>(hs2, rbeg, rend, csr, dinv, b2, out, N);
}

// Round 5
// 233.979 us; speedup vs baseline: 1.4377x; 1.0124x over previous
//
#include <hip/hip_runtime.h>
#include <hip/hip_bf16.h>

// GCN 2-layer forward. Pipeline (6 kernels):
//   prep          : zero bucket cursors + W1,W2 -> bf16 transposed + ZERO ROW
//   bin_edges     : edges -> bucket-strided PACKED u32 (src | dloc<<24)
//                   [r5: halves scattered-write volume vs int2]
//   build_csr     : per-bucket LDS histogram/prefix -> dinv, rbeg/rend, csr,
//                   AND u = bf16(z * dinv[:,None])
//   aggregate PRE : agg1_d = bf16(u_d + sum u_s)   (2 nodes/wave, interleaved
//                   16-wide batches, zero-row tail, NT store)
//   gemm12_mfma   : x1 = relu(dinv*(agg1@W1)+b1) in LDS (bf16);
//                   hs2 = bf16(dinv*(x1@W2))      (normal store: POST's table)
//   aggregate POST: out_d = dinv_d*(hs2_d + sum hs2_s) + b2  (fp32 NT store)
//
// Evidence log:
//  - r1: aggregate+GEMM fusion regressed (barrier idling, LDS occupancy cap).
//  - r1: two separate scatter streams (esrc+edloc) write-amplified 49MB.
//  - r2: address-clamped gather broke merged scalar index loads (77us).
//  - r3: aggregate FETCH 92MB ~= 8 XCDs x miss-stream of 12.8MB table.
//  - r4 counters: bin_edges = scattered-write plateau ~850GB/s (28MB for
//    12.8 logical). aggregate: 1 line per 15.5cy/CU, in-flight >> BW*latency
//    -> hypothesis: per-wave serial wait chains, tested here via 2 nodes/wave.

#define WAVE 64
#define BSHIFT 8
#define NPB 256              // nodes per bucket
#define CAP 5120             // max edges per bucket (mean 4096, +16 sigma)
#define CH 4096              // edges per WG in bin_edges
#define NBMAX 512

typedef __attribute__((ext_vector_type(8))) short bf16x8;
typedef __attribute__((ext_vector_type(4))) float f32x4;

__device__ inline float bf16_to_f32(unsigned short h) {
    return __uint_as_float(((unsigned int)h) << 16);
}
__device__ inline unsigned short f32_to_bf16(float f) {
    unsigned int x = __float_as_uint(f);
    return (unsigned short)((x + 0x7FFFu + ((x >> 16) & 1u)) >> 16);   // RNE
}

// ---------------- prep: zero cursors + W -> bf16 transposed + zero row ------
__global__ void prep(const float* __restrict__ W1, const float* __restrict__ W2,
                     unsigned short* __restrict__ W1t, unsigned short* __restrict__ W2t,
                     int* __restrict__ bcursor, int NB,
                     unsigned short* __restrict__ zr, int N)
{
    int i = blockIdx.x * blockDim.x + threadIdx.x;
    if (i < NB) bcursor[i] = 0;
    if (i < 64) zr[(size_t)N * 64 + i] = 0;   // zero row (gather tail target)
    if (i < 128 * 64) {          // W1t[n][k] = W1[k][n]  (W1 is [64][128])
        int n = i >> 6, k = i & 63;
        W1t[i] = f32_to_bf16(W1[k * 128 + n]);
    }
    if (i < 64 * 128) {          // W2t[n][k] = W2[k][n]  (W2 is [128][64])
        int n = i >> 7, k = i & 127;
        W2t[i] = f32_to_bf16(W2[k * 64 + n]);
    }
}

// ---------------- bin_edges: scatter edges, PACKED u32 per edge -------------
// One 4B store per edge: src (<2^17) in bits 0..23, local dst in bits 24..31.
// Single store stream (r1 lesson) at half of int2's bytes (r4 lesson: this
// kernel sits on the ~850GB/s scattered-write plateau -> volume is time).
__global__ __launch_bounds__(256) void bin_edges(
        const int* __restrict__ src, const int* __restrict__ dst,
        int* __restrict__ bcursor, unsigned int* __restrict__ ebuf, int E, int NB)
{
    __shared__ int hist[NBMAX];
    __shared__ int cur[NBMAX];
    const int t  = threadIdx.x;
    const int e0 = blockIdx.x * CH;

    for (int b = t; b < NB; b += 256) hist[b] = 0;
    __syncthreads();

#pragma unroll
    for (int j = 0; j < CH / 256; ++j) {
        int e = e0 + j * 256 + t;
        if (e < E) atomicAdd(&hist[dst[e] >> BSHIFT], 1);
    }
    __syncthreads();

    for (int b = t; b < NB; b += 256) {
        int c = hist[b];
        cur[b] = (c > 0) ? atomicAdd(&bcursor[b], c) : 0;
    }
    __syncthreads();

#pragma unroll
    for (int j = 0; j < CH / 256; ++j) {
        int e = e0 + j * 256 + t;
        if (e < E) {
            int s = src[e], d = dst[e];
            int b = d >> BSHIFT;
            int pos = atomicAdd(&cur[b], 1);
            ebuf[(size_t)b * CAP + pos] =
                (unsigned int)s | ((unsigned int)(d & (NPB - 1)) << 24);
        }
    }
}

// ---------------- build_csr + fused u = bf16(z*dinv) ------------------------
__global__ __launch_bounds__(256) void build_csr(
        const unsigned int* __restrict__ ebuf, const int* __restrict__ bcursor,
        const float* __restrict__ z, float* __restrict__ dinv,
        int* __restrict__ rbeg, int* __restrict__ rend,
        int* __restrict__ csr, unsigned short* __restrict__ u, int N)
{
    __shared__ int   h[NPB];
    __shared__ int   tmp[NPB];
    __shared__ float sdv[NPB];
    const int t   = threadIdx.x;
    const int b   = blockIdx.x;
    const int n0  = b << BSHIFT;
    const int cnt = bcursor[b];
    const size_t base = (size_t)b * CAP;

    h[t] = 0;
    __syncthreads();

    for (int i = t; i < cnt; i += 256)
        atomicAdd(&h[ebuf[base + i] >> 24], 1);
    __syncthreads();

    int deg = h[t];
    tmp[t] = deg;
    __syncthreads();
    for (int off = 1; off < 256; off <<= 1) {
        int x = (t >= off) ? tmp[t - off] : 0;
        __syncthreads();
        tmp[t] += x;
        __syncthreads();
    }
    int st = tmp[t] - deg;

    int node = n0 + t;
    float di = rsqrtf((float)deg + 1.0f);
    sdv[t] = di;
    if (node < N) {
        dinv[node] = di;
        rbeg[node] = (int)base + st;
        rend[node] = (int)base + st + deg;
    }
    h[t] = st;
    __syncthreads();   // covers h-cursor reset and sdv visibility

    for (int i = t; i < cnt; i += 256) {
        unsigned int w = ebuf[base + i];
        int p = atomicAdd(&h[w >> 24], 1);
        csr[base + p] = (int)(w & 0xFFFFFFu);
    }

    // fused scale: u rows for this bucket (16 threads per row, float4 reads)
    const int nloc = (N - n0 < NPB) ? (N - n0) : NPB;
    for (int i = t; i < nloc * 16; i += 256) {
        int r = i >> 4, kq = i & 15;
        float d2 = sdv[r];
        float4 v = ((const float4*)(z + (size_t)(n0 + r) * 64))[kq];
        ushort4 o;
        o.x = f32_to_bf16(v.x * d2);
        o.y = f32_to_bf16(v.y * d2);
        o.z = f32_to_bf16(v.z * d2);
        o.w = f32_to_bf16(v.w * d2);
        ((ushort4*)(u + (size_t)(n0 + r) * 64))[kq] = o;
    }
}

// ---------------- aggregate: TWO nodes per wave, interleaved batches --------
// Each wave owns nodes nA=2p, nB=2p+1. Per round, it issues 16 gathers for A
// AND 16 for B (32 independent lines) before one vmcnt wait -> per-CU serial
// wait rounds drop ~1.7x vs one node/wave. Index loads stay contiguous scalar
// (r2 lesson); tail slots redirected to zero row N AFTER the load (value-side).
// Per-node summation order identical to r4 (extra batches add exact +0.0).
// PRE  (POST=false): out = bf16(...)          -> ushort* NT store
// POST (POST=true):  out = dinv*(...) + b     -> float*  NT store
template<bool POST>
__global__ __launch_bounds__(256) void aggregate64_bf16(
        const unsigned short* __restrict__ hs, const int* __restrict__ rbeg,
        const int* __restrict__ rend, const int* __restrict__ csr,
        const float* __restrict__ dinv, const float* __restrict__ b,
        void* __restrict__ out_, int N)
{
    int pair = (int)((blockIdx.x * (size_t)blockDim.x + threadIdx.x) >> 6);
    const int lane = threadIdx.x & 63;
    int nA = pair * 2;
    if (nA >= N) return;
    nA = __builtin_amdgcn_readfirstlane(nA);   // wave-uniform -> scalar loads
    const int nBr = nA + 1;
    const bool hasB = (nBr < N);
    const int nB = hasB ? nBr : N;             // row N = zero row

    const int begA = rbeg[nA], endA = rend[nA];
    int begB = 0, endB = 0;
    if (hasB) { begB = rbeg[nBr]; endB = rend[nBr]; }

    float accA = bf16_to_f32(hs[(size_t)nA * 64 + lane]);   // self-loop terms
    float accB = bf16_to_f32(hs[(size_t)nB * 64 + lane]);

    int nbat = (endA - begA + 15) >> 4;
    int nbB  = (endB - begB + 15) >> 4;
    if (nbB > nbat) nbat = nbB;

    int eA = begA, eB = begB;
    for (int bt = 0; bt < nbat; ++bt, eA += 16, eB += 16) {
        int sA[16], sB[16];
#pragma unroll
        for (int j = 0; j < 16; ++j) sA[j] = csr[eA + j];   // contiguous scalar
#pragma unroll
        for (int j = 0; j < 16; ++j) sB[j] = csr[eB + j];
#pragma unroll
        for (int j = 0; j < 16; ++j) sA[j] = (eA + j < endA) ? sA[j] : N;
#pragma unroll
        for (int j = 0; j < 16; ++j) sB[j] = (eB + j < endB) ? sB[j] : N;
        float vA[16], vB[16];
#pragma unroll
        for (int j = 0; j < 16; ++j)
            vA[j] = bf16_to_f32(hs[(size_t)sA[j] * 64 + lane]);
#pragma unroll
        for (int j = 0; j < 16; ++j)
            vB[j] = bf16_to_f32(hs[(size_t)sB[j] * 64 + lane]);
        float a0 = ((vA[0]+vA[1])+(vA[2]+vA[3])) + ((vA[4]+vA[5])+(vA[6]+vA[7]));
        float a1 = ((vA[8]+vA[9])+(vA[10]+vA[11])) + ((vA[12]+vA[13])+(vA[14]+vA[15]));
        accA += a0 + a1;
        float c0 = ((vB[0]+vB[1])+(vB[2]+vB[3])) + ((vB[4]+vB[5])+(vB[6]+vB[7]));
        float c1 = ((vB[8]+vB[9])+(vB[10]+vB[11])) + ((vB[12]+vB[13])+(vB[14]+vB[15]));
        accB += c0 + c1;
    }

    if (POST) {
        float oA = dinv[nA] * accA + b[lane];
        __builtin_nontemporal_store(oA, &((float*)out_)[(size_t)nA * 64 + lane]);
        if (hasB) {
            float oB = dinv[nBr] * accB + b[lane];
            __builtin_nontemporal_store(oB, &((float*)out_)[(size_t)nBr * 64 + lane]);
        }
    } else {
        __builtin_nontemporal_store(f32_to_bf16(accA),
            &((unsigned short*)out_)[(size_t)nA * 64 + lane]);
        if (hasB)
            __builtin_nontemporal_store(f32_to_bf16(accB),
                &((unsigned short*)out_)[(size_t)nBr * 64 + lane]);
    }
}

// ---------------- fused dual GEMM on MFMA ----------------
// Per 32-row tile:
//   phase 1: x1 = relu(dinv*(agg1@W1)+b1)  -> LDS bf16 (A-operand layout)
//   phase 2: hs2 = bf16(dinv*(x1@W2))      -> global (normal store; gather table)
// mfma_f32_16x16x32_bf16 layouts (HW-verified, learn_hip m89/m91/m120):
//   A: lane holds A[m=lane&15][k = (lane>>4)*8 + j]  (8 contiguous bf16)
//   B: lane holds B[k=(lane>>4)*8+j][n=lane&15]  -> stage W transposed Wt[n][k]
//   C/D: col = lane&15, row = (lane>>4)*4 + reg
// LDS ~49.3 KB -> 3 WGs/CU. Padded strides (72/136 ushorts) keep reads ~2-way.
#define TILE 32
#define W1T_ST 72
#define W2T_ST 136
#define A_ST   72
#define X1_ST  136

__global__ __launch_bounds__(256) void gemm12_mfma(
        const unsigned short* __restrict__ agg1,   // bf16 [N][64]
        const unsigned short* __restrict__ W1t,    // bf16 [128][64]  (n-major)
        const float* __restrict__ b1,              // [128]
        const unsigned short* __restrict__ W2t,    // bf16 [64][128]  (n-major)
        const float* __restrict__ dinv,
        unsigned short* __restrict__ hs2, int N)
{
    __shared__ unsigned short sW1[128 * W1T_ST];
    __shared__ unsigned short sW2[64 * W2T_ST];
    __shared__ unsigned short sA[TILE * A_ST];
    __shared__ unsigned short sX[TILE * X1_ST];
    __shared__ float sdv[TILE];

    const int tid  = threadIdx.x;
    const int row0 = blockIdx.x * TILE;
    const int lane = tid & 63;
    const int wv   = tid >> 6;        // wave 0..3
    const int l16  = lane & 15;
    const int quad = lane >> 4;       // 0..3

    // ---- stage W1t (128 rows x 8 chunks of 8 bf16) ----
    for (int i = tid; i < 128 * 8; i += 256) {
        int r = i >> 3, c = i & 7;
        *(uint4*)&sW1[r * W1T_ST + c * 8] = *(const uint4*)&W1t[r * 64 + c * 8];
    }
    // ---- stage W2t (64 rows x 16 chunks) ----
    for (int i = tid; i < 64 * 16; i += 256) {
        int r = i >> 4, c = i & 15;
        *(uint4*)&sW2[r * W2T_ST + c * 8] = *(const uint4*)&W2t[r * 128 + c * 8];
    }
    // ---- stage A tile (32 rows x 8 chunks) ----
    for (int i = tid; i < TILE * 8; i += 256) {
        int r = i >> 3, c = i & 7;
        int gr = row0 + r;
        uint4 v = make_uint4(0u, 0u, 0u, 0u);
        if (gr < N) v = *(const uint4*)&agg1[(size_t)gr * 64 + c * 8];
        *(uint4*)&sA[r * A_ST + c * 8] = v;
    }
    if (tid < TILE) {
        int gr = row0 + tid;
        sdv[tid] = (gr < N) ? dinv[gr] : 0.0f;
    }
    __syncthreads();

    // ---- phase 1: 32x128 output, 16 MFMA tiles, 4 per wave ----
    {
        const int mt  = wv & 1;
        const int ntb = (wv >> 1) * 4;
        f32x4 acc[4];
#pragma unroll
        for (int t = 0; t < 4; ++t) acc[t] = (f32x4)0.0f;

#pragma unroll
        for (int k0 = 0; k0 < 64; k0 += 32) {
            bf16x8 af = *(const bf16x8*)&sA[(mt * 16 + l16) * A_ST + k0 + quad * 8];
#pragma unroll
            for (int t = 0; t < 4; ++t) {
                bf16x8 bf = *(const bf16x8*)&sW1[((ntb + t) * 16 + l16) * W1T_ST + k0 + quad * 8];
                acc[t] = __builtin_amdgcn_mfma_f32_16x16x32_bf16(af, bf, acc[t], 0, 0, 0);
            }
        }

#pragma unroll
        for (int t = 0; t < 4; ++t) {
            int col = (ntb + t) * 16 + l16;
            float bb = b1[col];
#pragma unroll
            for (int r = 0; r < 4; ++r) {
                int lr = mt * 16 + quad * 4 + r;
                float o = fmaxf(acc[t][r] * sdv[lr] + bb, 0.0f);
                sX[lr * X1_ST + col] = f32_to_bf16(o);
            }
        }
    }
    __syncthreads();

    // ---- phase 2: 32x64 output, 8 MFMA tiles, 2 per wave ----
    {
        const int mt  = wv & 1;
        const int ntb = (wv >> 1) * 2;
        f32x4 acc[2];
#pragma unroll
        for (int t = 0; t < 2; ++t) acc[t] = (f32x4)0.0f;

#pragma unroll
        for (int k0 = 0; k0 < 128; k0 += 32) {
            bf16x8 af = *(const bf16x8*)&sX[(mt * 16 + l16) * X1_ST + k0 + quad * 8];
#pragma unroll
            for (int t = 0; t < 2; ++t) {
                bf16x8 bf = *(const bf16x8*)&sW2[((ntb + t) * 16 + l16) * W2T_ST + k0 + quad * 8];
                acc[t] = __builtin_amdgcn_mfma_f32_16x16x32_bf16(af, bf, acc[t], 0, 0, 0);
            }
        }

#pragma unroll
        for (int t = 0; t < 2; ++t) {
            int col = (ntb + t) * 16 + l16;
#pragma unroll
            for (int r = 0; r < 4; ++r) {
                int lr = mt * 16 + quad * 4 + r;
                int gr = row0 + lr;
                if (gr < N)
                    hs2[(size_t)gr * 64 + col] = f32_to_bf16(acc[t][r] * sdv[lr]);
            }
        }
    }
}

static inline size_t align_up(size_t x, size_t a) { return (x + a - 1) / a * a; }

extern "C" void kernel_launch(void* const* d_in, const int* in_sizes, int n_in,
                              void* d_out, int out_size, void* d_ws, size_t ws_size,
                              hipStream_t stream) {
    const float* z    = (const float*)d_in[0];   // [N,64]
    const int*   eidx = (const int*)d_in[1];     // [2,E]: src row then dst row
    const float* W1   = (const float*)d_in[2];   // [64,128]
    const float* b1   = (const float*)d_in[3];   // [128]
    const float* W2   = (const float*)d_in[4];   // [128,64]
    const float* b2   = (const float*)d_in[5];   // [64]
    float* out = (float*)d_out;                  // [N,64]

    const int N = in_sizes[0] / 64;
    const int E = in_sizes[1] / 2;
    const int* src = eidx;
    const int* dst = eidx + E;
    const int NB = (N + NPB - 1) >> BSHIFT;      // 391 for N=100000

    // Workspace: small arrays | W1t | W2t | csr | bufA | bufB | bufC
    // u (bf16, N+1 rows incl. zero row) in bufA; agg1 (bf16) in bufB;
    // hs2 (bf16) overwrites u rows 0..N-1 in bufA -- row N (zero) survives
    // as the POST gather's tail target. ebuf (u32) aliases bufC.
    char* ws = (char*)d_ws;
    size_t off = 0;
    float* dinv    = (float*)(ws + off); off = align_up(off + (size_t)N * 4, 512);
    int*   rbeg    = (int*)  (ws + off); off = align_up(off + (size_t)N * 4, 512);
    int*   rend    = (int*)  (ws + off); off = align_up(off + (size_t)N * 4, 512);
    int*   bcursor = (int*)  (ws + off); off = align_up(off + (size_t)NBMAX * 4, 512);
    unsigned short* W1t = (unsigned short*)(ws + off); off = align_up(off + 8192 * 2, 512);
    unsigned short* W2t = (unsigned short*)(ws + off); off = align_up(off + 8192 * 2, 512);
    int*   csr     = (int*)  (ws + off); off = align_up(off + (size_t)NB * CAP * 4, 512);
    float* bufA    = (float*)(ws + off); off = align_up(off + (size_t)N * 64 * 4, 512);
    float* bufB    = (float*)(ws + off); off = align_up(off + (size_t)N * 64 * 4, 512);
    float* bufC    = (float*)(ws + off); off = align_up(off + (size_t)N * 128 * 4, 512);
    (void)ws_size;

    unsigned short* u    = (unsigned short*)bufA;   // bf16 z*dinv, rows 0..N (N = zero)
    unsigned short* agg1 = (unsigned short*)bufB;   // bf16 aggregated u
    unsigned short* hs2  = (unsigned short*)bufA;   // bf16 layer-2 pre-aggregate
    unsigned int*   ebuf = (unsigned int*)bufC;

    // ---- prep (cursor zero + W transpose/convert + zero row of u) ----
    prep<<<32, 256, 0, stream>>>(W1, W2, W1t, W2t, bcursor, NB, u, N);

    // ---- CSR build (+ fused dinv & u-scale) ----
    bin_edges<<<(E + CH - 1) / CH, 256, 0, stream>>>(src, dst, bcursor, ebuf, E, NB);
    build_csr<<<NB, 256, 0, stream>>>(ebuf, bcursor, z, dinv, rbeg, rend, csr, u, N);

    // ---- layer 1 aggregate (2 nodes/wave, interleaved batches, NT out) ----
    {
        int pairs = (N + 1) / 2;
        aggregate64_bf16<false><<<(pairs + 3) / 4, 256, 0, stream>>>(
            u, rbeg, rend, csr, dinv, nullptr, agg1, N);
    }

    // ---- fused dual GEMM on MFMA (x1 never leaves LDS) ----
    gemm12_mfma<<<(N + TILE - 1) / TILE, 256, 0, stream>>>(agg1, W1t, b1, W2t, dinv, hs2, N);

    // ---- layer 2 aggregate (2 nodes/wave, fp32 NT out) ----
    {
        int pairs = (N + 1) / 2;
        aggregate64_bf16<true><<<(pairs + 3) / 4, 256, 0, stream>>>(
            hs2, rbeg, rend, csr, dinv, b2, out, N);
    }
}

// Round 6
// 229.548 us; speedup vs baseline: 1.4655x; 1.0193x over previous
//
#include <hip/hip_runtime.h>
#include <hip/hip_bf16.h>

// GCN 2-layer forward. Pipeline (6 kernels):
//   prep          : zero bucket cursors + W1,W2 -> bf16 transposed + ZERO ROW
//   bin_edges     : edges -> bucket-strided PACKED u32 (src | dloc<<24)
//   build_csr     : per-bucket LDS histogram/prefix -> dinv, rbeg/rend, csr,
//                   AND u = bf16(z * dinv[:,None])
//   aggregate PRE : agg1_d = bf16(u_d + sum u_s)   (1 node/wave, 16-wide,
//                   zero-row tail, NT store)
//   gemm12_mfma   : x1 = relu(dinv*(agg1@W1)+b1) in LDS (bf16);
//                   hs2 = bf16(dinv*(x1@W2))      (normal store: POST's table)
//   aggregate POST: out_d = dinv_d*(hs2_d + sum hs2_s) + b2  (fp32 NT store)
//
// Evidence log:
//  - r1: aggregate+GEMM fusion regressed (barrier idling, LDS occupancy cap).
//  - r1: two separate scatter streams (esrc+edloc) write-amplified 49MB.
//  - r2: address-clamped gather broke merged scalar index loads (77us).
//  - r4: packed-u32 bin_edges halves scattered writes (confirmed r5: left top-5).
//  - r5: 2 nodes/wave aggregate REGRESSED (44.8 vs <=41.2us): not chain-bound.
//    Aggregate is at the structural floor: FETCH 86.9MB ~= 8 XCDs x 86% x
//    12.8MB table (compulsory, non-coherent L2s) at ~2TB/s random-128B-line
//    HBM ceiling. Reverted to 1 node/wave. fp8 rows would halve the floor but
//    blow the error budget; src-partitioned partial sums cost >100MB extra.

#define WAVE 64
#define BSHIFT 8
#define NPB 256              // nodes per bucket
#define CAP 5120             // max edges per bucket (mean 4096, +16 sigma)
#define CH 4096              // edges per WG in bin_edges
#define NBMAX 512

typedef __attribute__((ext_vector_type(8))) short bf16x8;
typedef __attribute__((ext_vector_type(4))) float f32x4;

__device__ inline float bf16_to_f32(unsigned short h) {
    return __uint_as_float(((unsigned int)h) << 16);
}
__device__ inline unsigned short f32_to_bf16(float f) {
    unsigned int x = __float_as_uint(f);
    return (unsigned short)((x + 0x7FFFu + ((x >> 16) & 1u)) >> 16);   // RNE
}

// 16-wide gather with zero-row tail: acc += sum of bf16 rows hs[csr[e]][lane].
// Indices loaded contiguously (wave-uniform -> merged scalar loads), THEN the
// overhang is redirected to row `zrow` (a dedicated all-zero row, L1-hot).
__device__ inline float gather_rows16(const unsigned short* __restrict__ hs,
                                      const int* __restrict__ csr,
                                      int beg, int end, int lane, int zrow,
                                      float acc)
{
    for (int e = beg; e < end; e += 16) {
        int s[16];
#pragma unroll
        for (int j = 0; j < 16; ++j) s[j] = csr[e + j];   // contiguous, unconditional
#pragma unroll
        for (int j = 0; j < 16; ++j)
            s[j] = (e + j < end) ? s[j] : zrow;           // scalar cselect AFTER load
        float v[16];
#pragma unroll
        for (int j = 0; j < 16; ++j)
            v[j] = bf16_to_f32(hs[(size_t)s[j] * 64 + lane]);
        float t0 = ((v[0] + v[1]) + (v[2] + v[3])) + ((v[4] + v[5]) + (v[6] + v[7]));
        float t1 = ((v[8] + v[9]) + (v[10] + v[11])) + ((v[12] + v[13]) + (v[14] + v[15]));
        acc += t0 + t1;
    }
    return acc;
}

// ---------------- prep: zero cursors + W -> bf16 transposed + zero row ------
__global__ void prep(const float* __restrict__ W1, const float* __restrict__ W2,
                     unsigned short* __restrict__ W1t, unsigned short* __restrict__ W2t,
                     int* __restrict__ bcursor, int NB,
                     unsigned short* __restrict__ zr, int N)
{
    int i = blockIdx.x * blockDim.x + threadIdx.x;
    if (i < NB) bcursor[i] = 0;
    if (i < 64) zr[(size_t)N * 64 + i] = 0;   // zero row (gather tail target)
    if (i < 128 * 64) {          // W1t[n][k] = W1[k][n]  (W1 is [64][128])
        int n = i >> 6, k = i & 63;
        W1t[i] = f32_to_bf16(W1[k * 128 + n]);
    }
    if (i < 64 * 128) {          // W2t[n][k] = W2[k][n]  (W2 is [128][64])
        int n = i >> 7, k = i & 127;
        W2t[i] = f32_to_bf16(W2[k * 64 + n]);
    }
}

// ---------------- bin_edges: scatter edges, PACKED u32 per edge -------------
// One 4B store per edge: src (<2^17) in bits 0..23, local dst in bits 24..31.
// Single store stream (r1 lesson) at half of int2's bytes (r4 lesson: this
// kernel sits on the ~850GB/s scattered-write plateau -> volume is time).
__global__ __launch_bounds__(256) void bin_edges(
        const int* __restrict__ src, const int* __restrict__ dst,
        int* __restrict__ bcursor, unsigned int* __restrict__ ebuf, int E, int NB)
{
    __shared__ int hist[NBMAX];
    __shared__ int cur[NBMAX];
    const int t  = threadIdx.x;
    const int e0 = blockIdx.x * CH;

    for (int b = t; b < NB; b += 256) hist[b] = 0;
    __syncthreads();

#pragma unroll
    for (int j = 0; j < CH / 256; ++j) {
        int e = e0 + j * 256 + t;
        if (e < E) atomicAdd(&hist[dst[e] >> BSHIFT], 1);
    }
    __syncthreads();

    for (int b = t; b < NB; b += 256) {
        int c = hist[b];
        cur[b] = (c > 0) ? atomicAdd(&bcursor[b], c) : 0;
    }
    __syncthreads();

#pragma unroll
    for (int j = 0; j < CH / 256; ++j) {
        int e = e0 + j * 256 + t;
        if (e < E) {
            int s = src[e], d = dst[e];
            int b = d >> BSHIFT;
            int pos = atomicAdd(&cur[b], 1);
            ebuf[(size_t)b * CAP + pos] =
                (unsigned int)s | ((unsigned int)(d & (NPB - 1)) << 24);
        }
    }
}

// ---------------- build_csr + fused u = bf16(z*dinv) ------------------------
__global__ __launch_bounds__(256) void build_csr(
        const unsigned int* __restrict__ ebuf, const int* __restrict__ bcursor,
        const float* __restrict__ z, float* __restrict__ dinv,
        int* __restrict__ rbeg, int* __restrict__ rend,
        int* __restrict__ csr, unsigned short* __restrict__ u, int N)
{
    __shared__ int   h[NPB];
    __shared__ int   tmp[NPB];
    __shared__ float sdv[NPB];
    const int t   = threadIdx.x;
    const int b   = blockIdx.x;
    const int n0  = b << BSHIFT;
    const int cnt = bcursor[b];
    const size_t base = (size_t)b * CAP;

    h[t] = 0;
    __syncthreads();

    for (int i = t; i < cnt; i += 256)
        atomicAdd(&h[ebuf[base + i] >> 24], 1);
    __syncthreads();

    int deg = h[t];
    tmp[t] = deg;
    __syncthreads();
    for (int off = 1; off < 256; off <<= 1) {
        int x = (t >= off) ? tmp[t - off] : 0;
        __syncthreads();
        tmp[t] += x;
        __syncthreads();
    }
    int st = tmp[t] - deg;

    int node = n0 + t;
    float di = rsqrtf((float)deg + 1.0f);
    sdv[t] = di;
    if (node < N) {
        dinv[node] = di;
        rbeg[node] = (int)base + st;
        rend[node] = (int)base + st + deg;
    }
    h[t] = st;
    __syncthreads();   // covers h-cursor reset and sdv visibility

    for (int i = t; i < cnt; i += 256) {
        unsigned int w = ebuf[base + i];
        int p = atomicAdd(&h[w >> 24], 1);
        csr[base + p] = (int)(w & 0xFFFFFFu);
    }

    // fused scale: u rows for this bucket (16 threads per row, float4 reads)
    const int nloc = (N - n0 < NPB) ? (N - n0) : NPB;
    for (int i = t; i < nloc * 16; i += 256) {
        int r = i >> 4, kq = i & 15;
        float d2 = sdv[r];
        float4 v = ((const float4*)(z + (size_t)(n0 + r) * 64))[kq];
        ushort4 o;
        o.x = f32_to_bf16(v.x * d2);
        o.y = f32_to_bf16(v.y * d2);
        o.z = f32_to_bf16(v.z * d2);
        o.w = f32_to_bf16(v.w * d2);
        ((ushort4*)(u + (size_t)(n0 + r) * 64))[kq] = o;
    }
}

// ---------------- aggregate (F=64, bf16 rows), ONE node per wave ------------
// r5 lesson: 2 nodes/wave regressed; the gather is at the compulsory random-
// line HBM floor, so maximize wave count (TLP) and keep VGPR low.
// PRE  (POST=false): out = bf16(hs_d + sum hs_s)        -> ushort* NT store
// POST (POST=true):  out = dinv_d*(hs_d + sum hs_s) + b -> float*  NT store
template<bool POST>
__global__ __launch_bounds__(256) void aggregate64_bf16(
        const unsigned short* __restrict__ hs, const int* __restrict__ rbeg,
        const int* __restrict__ rend, const int* __restrict__ csr,
        const float* __restrict__ dinv, const float* __restrict__ b,
        void* __restrict__ out_, int N)
{
    int node = (int)((blockIdx.x * (size_t)blockDim.x + threadIdx.x) >> 6);
    int lane = threadIdx.x & 63;
    if (node >= N) return;
    node = __builtin_amdgcn_readfirstlane(node);   // wave-uniform -> scalar loads

    const int beg = rbeg[node];
    const int end = rend[node];

    float acc = bf16_to_f32(hs[(size_t)node * 64 + lane]);   // self-loop term
    acc = gather_rows16(hs, csr, beg, end, lane, N, acc);    // row N == zero row

    if (POST) {
        float o = dinv[node] * acc + b[lane];
        __builtin_nontemporal_store(o, &((float*)out_)[(size_t)node * 64 + lane]);
    } else {
        __builtin_nontemporal_store(f32_to_bf16(acc),
            &((unsigned short*)out_)[(size_t)node * 64 + lane]);
    }
}

// ---------------- fused dual GEMM on MFMA ----------------
// Per 32-row tile:
//   phase 1: x1 = relu(dinv*(agg1@W1)+b1)  -> LDS bf16 (A-operand layout)
//   phase 2: hs2 = bf16(dinv*(x1@W2))      -> global (normal store; gather table)
// mfma_f32_16x16x32_bf16 layouts (HW-verified, learn_hip m89/m91/m120):
//   A: lane holds A[m=lane&15][k = (lane>>4)*8 + j]  (8 contiguous bf16)
//   B: lane holds B[k=(lane>>4)*8+j][n=lane&15]  -> stage W transposed Wt[n][k]
//   C/D: col = lane&15, row = (lane>>4)*4 + reg
// LDS ~49.3 KB -> 3 WGs/CU. Padded strides (72/136 ushorts) keep reads ~2-way.
#define TILE 32
#define W1T_ST 72
#define W2T_ST 136
#define A_ST   72
#define X1_ST  136

__global__ __launch_bounds__(256) void gemm12_mfma(
        const unsigned short* __restrict__ agg1,   // bf16 [N][64]
        const unsigned short* __restrict__ W1t,    // bf16 [128][64]  (n-major)
        const float* __restrict__ b1,              // [128]
        const unsigned short* __restrict__ W2t,    // bf16 [64][128]  (n-major)
        const float* __restrict__ dinv,
        unsigned short* __restrict__ hs2, int N)
{
    __shared__ unsigned short sW1[128 * W1T_ST];
    __shared__ unsigned short sW2[64 * W2T_ST];
    __shared__ unsigned short sA[TILE * A_ST];
    __shared__ unsigned short sX[TILE * X1_ST];
    __shared__ float sdv[TILE];

    const int tid  = threadIdx.x;
    const int row0 = blockIdx.x * TILE;
    const int lane = tid & 63;
    const int wv   = tid >> 6;        // wave 0..3
    const int l16  = lane & 15;
    const int quad = lane >> 4;       // 0..3

    // ---- stage W1t (128 rows x 8 chunks of 8 bf16) ----
    for (int i = tid; i < 128 * 8; i += 256) {
        int r = i >> 3, c = i & 7;
        *(uint4*)&sW1[r * W1T_ST + c * 8] = *(const uint4*)&W1t[r * 64 + c * 8];
    }
    // ---- stage W2t (64 rows x 16 chunks) ----
    for (int i = tid; i < 64 * 16; i += 256) {
        int r = i >> 4, c = i & 15;
        *(uint4*)&sW2[r * W2T_ST + c * 8] = *(const uint4*)&W2t[r * 128 + c * 8];
    }
    // ---- stage A tile (32 rows x 8 chunks) ----
    for (int i = tid; i < TILE * 8; i += 256) {
        int r = i >> 3, c = i & 7;
        int gr = row0 + r;
        uint4 v = make_uint4(0u, 0u, 0u, 0u);
        if (gr < N) v = *(const uint4*)&agg1[(size_t)gr * 64 + c * 8];
        *(uint4*)&sA[r * A_ST + c * 8] = v;
    }
    if (tid < TILE) {
        int gr = row0 + tid;
        sdv[tid] = (gr < N) ? dinv[gr] : 0.0f;
    }
    __syncthreads();

    // ---- phase 1: 32x128 output, 16 MFMA tiles, 4 per wave ----
    {
        const int mt  = wv & 1;
        const int ntb = (wv >> 1) * 4;
        f32x4 acc[4];
#pragma unroll
        for (int t = 0; t < 4; ++t) acc[t] = (f32x4)0.0f;

#pragma unroll
        for (int k0 = 0; k0 < 64; k0 += 32) {
            bf16x8 af = *(const bf16x8*)&sA[(mt * 16 + l16) * A_ST + k0 + quad * 8];
#pragma unroll
            for (int t = 0; t < 4; ++t) {
                bf16x8 bf = *(const bf16x8*)&sW1[((ntb + t) * 16 + l16) * W1T_ST + k0 + quad * 8];
                acc[t] = __builtin_amdgcn_mfma_f32_16x16x32_bf16(af, bf, acc[t], 0, 0, 0);
            }
        }

#pragma unroll
        for (int t = 0; t < 4; ++t) {
            int col = (ntb + t) * 16 + l16;
            float bb = b1[col];
#pragma unroll
            for (int r = 0; r < 4; ++r) {
                int lr = mt * 16 + quad * 4 + r;
                float o = fmaxf(acc[t][r] * sdv[lr] + bb, 0.0f);
                sX[lr * X1_ST + col] = f32_to_bf16(o);
            }
        }
    }
    __syncthreads();

    // ---- phase 2: 32x64 output, 8 MFMA tiles, 2 per wave ----
    {
        const int mt  = wv & 1;
        const int ntb = (wv >> 1) * 2;
        f32x4 acc[2];
#pragma unroll
        for (int t = 0; t < 2; ++t) acc[t] = (f32x4)0.0f;

#pragma unroll
        for (int k0 = 0; k0 < 128; k0 += 32) {
            bf16x8 af = *(const bf16x8*)&sX[(mt * 16 + l16) * X1_ST + k0 + quad * 8];
#pragma unroll
            for (int t = 0; t < 2; ++t) {
                bf16x8 bf = *(const bf16x8*)&sW2[((ntb + t) * 16 + l16) * W2T_ST + k0 + quad * 8];
                acc[t] = __builtin_amdgcn_mfma_f32_16x16x32_bf16(af, bf, acc[t], 0, 0, 0);
            }
        }

#pragma unroll
        for (int t = 0; t < 2; ++t) {
            int col = (ntb + t) * 16 + l16;
#pragma unroll
            for (int r = 0; r < 4; ++r) {
                int lr = mt * 16 + quad * 4 + r;
                int gr = row0 + lr;
                if (gr < N)
                    hs2[(size_t)gr * 64 + col] = f32_to_bf16(acc[t][r] * sdv[lr]);
            }
        }
    }
}

static inline size_t align_up(size_t x, size_t a) { return (x + a - 1) / a * a; }

extern "C" void kernel_launch(void* const* d_in, const int* in_sizes, int n_in,
                              void* d_out, int out_size, void* d_ws, size_t ws_size,
                              hipStream_t stream) {
    const float* z    = (const float*)d_in[0];   // [N,64]
    const int*   eidx = (const int*)d_in[1];     // [2,E]: src row then dst row
    const float* W1   = (const float*)d_in[2];   // [64,128]
    const float* b1   = (const float*)d_in[3];   // [128]
    const float* W2   = (const float*)d_in[4];   // [128,64]
    const float* b2   = (const float*)d_in[5];   // [64]
    float* out = (float*)d_out;                  // [N,64]

    const int N = in_sizes[0] / 64;
    const int E = in_sizes[1] / 2;
    const int* src = eidx;
    const int* dst = eidx + E;
    const int NB = (N + NPB - 1) >> BSHIFT;      // 391 for N=100000

    // Workspace: small arrays | W1t | W2t | csr | bufA | bufB | bufC
    // u (bf16, N+1 rows incl. zero row) in bufA; agg1 (bf16) in bufB;
    // hs2 (bf16) overwrites u rows 0..N-1 in bufA -- row N (zero) survives
    // as the POST gather's tail target. ebuf (u32) aliases bufC.
    char* ws = (char*)d_ws;
    size_t off = 0;
    float* dinv    = (float*)(ws + off); off = align_up(off + (size_t)N * 4, 512);
    int*   rbeg    = (int*)  (ws + off); off = align_up(off + (size_t)N * 4, 512);
    int*   rend    = (int*)  (ws + off); off = align_up(off + (size_t)N * 4, 512);
    int*   bcursor = (int*)  (ws + off); off = align_up(off + (size_t)NBMAX * 4, 512);
    unsigned short* W1t = (unsigned short*)(ws + off); off = align_up(off + 8192 * 2, 512);
    unsigned short* W2t = (unsigned short*)(ws + off); off = align_up(off + 8192 * 2, 512);
    int*   csr     = (int*)  (ws + off); off = align_up(off + (size_t)NB * CAP * 4, 512);
    float* bufA    = (float*)(ws + off); off = align_up(off + (size_t)N * 64 * 4, 512);
    float* bufB    = (float*)(ws + off); off = align_up(off + (size_t)N * 64 * 4, 512);
    float* bufC    = (float*)(ws + off); off = align_up(off + (size_t)N * 128 * 4, 512);
    (void)ws_size;

    unsigned short* u    = (unsigned short*)bufA;   // bf16 z*dinv, rows 0..N (N = zero)
    unsigned short* agg1 = (unsigned short*)bufB;   // bf16 aggregated u
    unsigned short* hs2  = (unsigned short*)bufA;   // bf16 layer-2 pre-aggregate
    unsigned int*   ebuf = (unsigned int*)bufC;

    // ---- prep (cursor zero + W transpose/convert + zero row of u) ----
    prep<<<32, 256, 0, stream>>>(W1, W2, W1t, W2t, bcursor, NB, u, N);

    // ---- CSR build (+ fused dinv & u-scale) ----
    bin_edges<<<(E + CH - 1) / CH, 256, 0, stream>>>(src, dst, bcursor, ebuf, E, NB);
    build_csr<<<NB, 256, 0, stream>>>(ebuf, bcursor, z, dinv, rbeg, rend, csr, u, N);

    // ---- layer 1 aggregate (1 node/wave, 16-wide zero-row gather, NT out) ----
    aggregate64_bf16<false><<<(N + 3) / 4, 256, 0, stream>>>(u, rbeg, rend, csr, dinv, nullptr, agg1, N);

    // ---- fused dual GEMM on MFMA (x1 never leaves LDS) ----
    gemm12_mfma<<<(N + TILE - 1) / TILE, 256, 0, stream>>>(agg1, W1t, b1, W2t, dinv, hs2, N);

    // ---- layer 2 aggregate (1 node/wave, fp32 NT out) ----
    aggregate64_bf16<true><<<(N + 3) / 4, 256, 0, stream>>>(hs2, rbeg, rend, csr, dinv, b2, out, N);
}

// Round 7
// 226.201 us; speedup vs baseline: 1.4871x; 1.0148x over previous
//
#include <hip/hip_runtime.h>
#include <hip/hip_bf16.h>

// GCN 2-layer forward. Pipeline (6 kernels):
//   prep          : zero bucket cursors + W1,W2 -> bf16 transposed + ZERO ROW
//   bin_edges     : edges -> bucket-strided PACKED u32 (src | dloc<<24)
//                   [r7: CH=8192, 512 threads -> 2x longer per-bucket runs,
//                   halves boundary-line write duplication]
//   build_csr     : per-bucket LDS histogram/prefix -> dinv, rbeg/rend, csr,
//                   AND u = bf16(z * dinv[:,None])
//   aggregate PRE : agg1_d = bf16(u_d + sum u_s)   (1 node/wave, 16-wide,
//                   zero-row tail, NT store)
//   gemm12_mfma   : x1 = relu(dinv*(agg1@W1)+b1) in LDS (bf16);
//                   hs2 = bf16(dinv*(x1@W2))      (normal store: POST's table)
//   aggregate POST: out_d = dinv_d*(hs2_d + sum hs2_s) + b2  (fp32 NT store)
//
// Evidence log:
//  - r1: aggregate+GEMM fusion regressed (barrier idling, LDS occupancy cap).
//  - r1: two separate scatter streams (esrc+edloc) write-amplified 49MB.
//  - r2: address-clamped gather broke merged scalar index loads (77us).
//  - r4: packed-u32 bin_edges halves scattered writes (confirmed r5/r6).
//  - r5: 2 nodes/wave aggregate REGRESSED: gather is at the structural floor
//    (FETCH ~87MB = 8 XCDs x ~86% x 12.8MB table, compulsory w/ non-coherent
//    L2s, at the ~2.2TB/s random-128B-line ceiling). 1 node/wave is optimal.
//  - r6: top-5 all harness fills (84us fixed). bin_edges write model:
//    writes ~= logical + 128B x run-boundary count -> longer runs = less time.

#define WAVE 64
#define BSHIFT 8
#define NPB 256              // nodes per bucket
#define CAP 5120             // max edges per bucket (mean 4096, +16 sigma)
#define CH 8192              // edges per WG in bin_edges (r7: was 4096)
#define BT 512               // bin_edges threads (r7: was 256)
#define NBMAX 512

typedef __attribute__((ext_vector_type(8))) short bf16x8;
typedef __attribute__((ext_vector_type(4))) float f32x4;

__device__ inline float bf16_to_f32(unsigned short h) {
    return __uint_as_float(((unsigned int)h) << 16);
}
__device__ inline unsigned short f32_to_bf16(float f) {
    unsigned int x = __float_as_uint(f);
    return (unsigned short)((x + 0x7FFFu + ((x >> 16) & 1u)) >> 16);   // RNE
}

// 16-wide gather with zero-row tail: acc += sum of bf16 rows hs[csr[e]][lane].
// Indices loaded contiguously (wave-uniform -> merged scalar loads), THEN the
// overhang is redirected to row `zrow` (a dedicated all-zero row, L1-hot).
__device__ inline float gather_rows16(const unsigned short* __restrict__ hs,
                                      const int* __restrict__ csr,
                                      int beg, int end, int lane, int zrow,
                                      float acc)
{
    for (int e = beg; e < end; e += 16) {
        int s[16];
#pragma unroll
        for (int j = 0; j < 16; ++j) s[j] = csr[e + j];   // contiguous, unconditional
#pragma unroll
        for (int j = 0; j < 16; ++j)
            s[j] = (e + j < end) ? s[j] : zrow;           // scalar cselect AFTER load
        float v[16];
#pragma unroll
        for (int j = 0; j < 16; ++j)
            v[j] = bf16_to_f32(hs[(size_t)s[j] * 64 + lane]);
        float t0 = ((v[0] + v[1]) + (v[2] + v[3])) + ((v[4] + v[5]) + (v[6] + v[7]));
        float t1 = ((v[8] + v[9]) + (v[10] + v[11])) + ((v[12] + v[13]) + (v[14] + v[15]));
        acc += t0 + t1;
    }
    return acc;
}

// ---------------- prep: zero cursors + W -> bf16 transposed + zero row ------
__global__ void prep(const float* __restrict__ W1, const float* __restrict__ W2,
                     unsigned short* __restrict__ W1t, unsigned short* __restrict__ W2t,
                     int* __restrict__ bcursor, int NB,
                     unsigned short* __restrict__ zr, int N)
{
    int i = blockIdx.x * blockDim.x + threadIdx.x;
    if (i < NB) bcursor[i] = 0;
    if (i < 64) zr[(size_t)N * 64 + i] = 0;   // zero row (gather tail target)
    if (i < 128 * 64) {          // W1t[n][k] = W1[k][n]  (W1 is [64][128])
        int n = i >> 6, k = i & 63;
        W1t[i] = f32_to_bf16(W1[k * 128 + n]);
    }
    if (i < 64 * 128) {          // W2t[n][k] = W2[k][n]  (W2 is [128][64])
        int n = i >> 7, k = i & 127;
        W2t[i] = f32_to_bf16(W2[k * 64 + n]);
    }
}

// ---------------- bin_edges: scatter edges, PACKED u32 per edge -------------
// One 4B store per edge: src (<2^17) in bits 0..23, local dst in bits 24..31.
// CH=8192/512thr: per-WG per-bucket runs ~21 edges (84B) -> halves the count
// of boundary lines shared between WGs on different XCDs (the write-amp term).
__global__ __launch_bounds__(BT) void bin_edges(
        const int* __restrict__ src, const int* __restrict__ dst,
        int* __restrict__ bcursor, unsigned int* __restrict__ ebuf, int E, int NB)
{
    __shared__ int hist[NBMAX];
    __shared__ int cur[NBMAX];
    const int t  = threadIdx.x;
    const int e0 = blockIdx.x * CH;

    for (int b = t; b < NB; b += BT) hist[b] = 0;
    __syncthreads();

#pragma unroll
    for (int j = 0; j < CH / BT; ++j) {
        int e = e0 + j * BT + t;
        if (e < E) atomicAdd(&hist[dst[e] >> BSHIFT], 1);
    }
    __syncthreads();

    for (int b = t; b < NB; b += BT) {
        int c = hist[b];
        cur[b] = (c > 0) ? atomicAdd(&bcursor[b], c) : 0;
    }
    __syncthreads();

#pragma unroll
    for (int j = 0; j < CH / BT; ++j) {
        int e = e0 + j * BT + t;
        if (e < E) {
            int s = src[e], d = dst[e];
            int b = d >> BSHIFT;
            int pos = atomicAdd(&cur[b], 1);
            ebuf[(size_t)b * CAP + pos] =
                (unsigned int)s | ((unsigned int)(d & (NPB - 1)) << 24);
        }
    }
}

// ---------------- build_csr + fused u = bf16(z*dinv) ------------------------
__global__ __launch_bounds__(256) void build_csr(
        const unsigned int* __restrict__ ebuf, const int* __restrict__ bcursor,
        const float* __restrict__ z, float* __restrict__ dinv,
        int* __restrict__ rbeg, int* __restrict__ rend,
        int* __restrict__ csr, unsigned short* __restrict__ u, int N)
{
    __shared__ int   h[NPB];
    __shared__ int   tmp[NPB];
    __shared__ float sdv[NPB];
    const int t   = threadIdx.x;
    const int b   = blockIdx.x;
    const int n0  = b << BSHIFT;
    const int cnt = bcursor[b];
    const size_t base = (size_t)b * CAP;

    h[t] = 0;
    __syncthreads();

    for (int i = t; i < cnt; i += 256)
        atomicAdd(&h[ebuf[base + i] >> 24], 1);
    __syncthreads();

    int deg = h[t];
    tmp[t] = deg;
    __syncthreads();
    for (int off = 1; off < 256; off <<= 1) {
        int x = (t >= off) ? tmp[t - off] : 0;
        __syncthreads();
        tmp[t] += x;
        __syncthreads();
    }
    int st = tmp[t] - deg;

    int node = n0 + t;
    float di = rsqrtf((float)deg + 1.0f);
    sdv[t] = di;
    if (node < N) {
        dinv[node] = di;
        rbeg[node] = (int)base + st;
        rend[node] = (int)base + st + deg;
    }
    h[t] = st;
    __syncthreads();   // covers h-cursor reset and sdv visibility

    for (int i = t; i < cnt; i += 256) {
        unsigned int w = ebuf[base + i];
        int p = atomicAdd(&h[w >> 24], 1);
        csr[base + p] = (int)(w & 0xFFFFFFu);
    }

    // fused scale: u rows for this bucket (16 threads per row, float4 reads)
    const int nloc = (N - n0 < NPB) ? (N - n0) : NPB;
    for (int i = t; i < nloc * 16; i += 256) {
        int r = i >> 4, kq = i & 15;
        float d2 = sdv[r];
        float4 v = ((const float4*)(z + (size_t)(n0 + r) * 64))[kq];
        ushort4 o;
        o.x = f32_to_bf16(v.x * d2);
        o.y = f32_to_bf16(v.y * d2);
        o.z = f32_to_bf16(v.z * d2);
        o.w = f32_to_bf16(v.w * d2);
        ((ushort4*)(u + (size_t)(n0 + r) * 64))[kq] = o;
    }
}

// ---------------- aggregate (F=64, bf16 rows), ONE node per wave ------------
// r5 lesson: 2 nodes/wave regressed; the gather is at the compulsory random-
// line HBM floor, so maximize wave count (TLP) and keep VGPR low.
// PRE  (POST=false): out = bf16(hs_d + sum hs_s)        -> ushort* NT store
// POST (POST=true):  out = dinv_d*(hs_d + sum hs_s) + b -> float*  NT store
template<bool POST>
__global__ __launch_bounds__(256) void aggregate64_bf16(
        const unsigned short* __restrict__ hs, const int* __restrict__ rbeg,
        const int* __restrict__ rend, const int* __restrict__ csr,
        const float* __restrict__ dinv, const float* __restrict__ b,
        void* __restrict__ out_, int N)
{
    int node = (int)((blockIdx.x * (size_t)blockDim.x + threadIdx.x) >> 6);
    int lane = threadIdx.x & 63;
    if (node >= N) return;
    node = __builtin_amdgcn_readfirstlane(node);   // wave-uniform -> scalar loads

    const int beg = rbeg[node];
    const int end = rend[node];

    float acc = bf16_to_f32(hs[(size_t)node * 64 + lane]);   // self-loop term
    acc = gather_rows16(hs, csr, beg, end, lane, N, acc);    // row N == zero row

    if (POST) {
        float o = dinv[node] * acc + b[lane];
        __builtin_nontemporal_store(o, &((float*)out_)[(size_t)node * 64 + lane]);
    } else {
        __builtin_nontemporal_store(f32_to_bf16(acc),
            &((unsigned short*)out_)[(size_t)node * 64 + lane]);
    }
}

// ---------------- fused dual GEMM on MFMA ----------------
// Per 32-row tile:
//   phase 1: x1 = relu(dinv*(agg1@W1)+b1)  -> LDS bf16 (A-operand layout)
//   phase 2: hs2 = bf16(dinv*(x1@W2))      -> global (normal store; gather table)
// mfma_f32_16x16x32_bf16 layouts (HW-verified, learn_hip m89/m91/m120):
//   A: lane holds A[m=lane&15][k = (lane>>4)*8 + j]  (8 contiguous bf16)
//   B: lane holds B[k=(lane>>4)*8+j][n=lane&15]  -> stage W transposed Wt[n][k]
//   C/D: col = lane&15, row = (lane>>4)*4 + reg
// LDS ~49.3 KB -> 3 WGs/CU. Padded strides (72/136 ushorts) keep reads ~2-way.
#define TILE 32
#define W1T_ST 72
#define W2T_ST 136
#define A_ST   72
#define X1_ST  136

__global__ __launch_bounds__(256) void gemm12_mfma(
        const unsigned short* __restrict__ agg1,   // bf16 [N][64]
        const unsigned short* __restrict__ W1t,    // bf16 [128][64]  (n-major)
        const float* __restrict__ b1,              // [128]
        const unsigned short* __restrict__ W2t,    // bf16 [64][128]  (n-major)
        const float* __restrict__ dinv,
        unsigned short* __restrict__ hs2, int N)
{
    __shared__ unsigned short sW1[128 * W1T_ST];
    __shared__ unsigned short sW2[64 * W2T_ST];
    __shared__ unsigned short sA[TILE * A_ST];
    __shared__ unsigned short sX[TILE * X1_ST];
    __shared__ float sdv[TILE];

    const int tid  = threadIdx.x;
    const int row0 = blockIdx.x * TILE;
    const int lane = tid & 63;
    const int wv   = tid >> 6;        // wave 0..3
    const int l16  = lane & 15;
    const int quad = lane >> 4;       // 0..3

    // ---- stage W1t (128 rows x 8 chunks of 8 bf16) ----
    for (int i = tid; i < 128 * 8; i += 256) {
        int r = i >> 3, c = i & 7;
        *(uint4*)&sW1[r * W1T_ST + c * 8] = *(const uint4*)&W1t[r * 64 + c * 8];
    }
    // ---- stage W2t (64 rows x 16 chunks) ----
    for (int i = tid; i < 64 * 16; i += 256) {
        int r = i >> 4, c = i & 15;
        *(uint4*)&sW2[r * W2T_ST + c * 8] = *(const uint4*)&W2t[r * 128 + c * 8];
    }
    // ---- stage A tile (32 rows x 8 chunks) ----
    for (int i = tid; i < TILE * 8; i += 256) {
        int r = i >> 3, c = i & 7;
        int gr = row0 + r;
        uint4 v = make_uint4(0u, 0u, 0u, 0u);
        if (gr < N) v = *(const uint4*)&agg1[(size_t)gr * 64 + c * 8];
        *(uint4*)&sA[r * A_ST + c * 8] = v;
    }
    if (tid < TILE) {
        int gr = row0 + tid;
        sdv[tid] = (gr < N) ? dinv[gr] : 0.0f;
    }
    __syncthreads();

    // ---- phase 1: 32x128 output, 16 MFMA tiles, 4 per wave ----
    {
        const int mt  = wv & 1;
        const int ntb = (wv >> 1) * 4;
        f32x4 acc[4];
#pragma unroll
        for (int t = 0; t < 4; ++t) acc[t] = (f32x4)0.0f;

#pragma unroll
        for (int k0 = 0; k0 < 64; k0 += 32) {
            bf16x8 af = *(const bf16x8*)&sA[(mt * 16 + l16) * A_ST + k0 + quad * 8];
#pragma unroll
            for (int t = 0; t < 4; ++t) {
                bf16x8 bf = *(const bf16x8*)&sW1[((ntb + t) * 16 + l16) * W1T_ST + k0 + quad * 8];
                acc[t] = __builtin_amdgcn_mfma_f32_16x16x32_bf16(af, bf, acc[t], 0, 0, 0);
            }
        }

#pragma unroll
        for (int t = 0; t < 4; ++t) {
            int col = (ntb + t) * 16 + l16;
            float bb = b1[col];
#pragma unroll
            for (int r = 0; r < 4; ++r) {
                int lr = mt * 16 + quad * 4 + r;
                float o = fmaxf(acc[t][r] * sdv[lr] + bb, 0.0f);
                sX[lr * X1_ST + col] = f32_to_bf16(o);
            }
        }
    }
    __syncthreads();

    // ---- phase 2: 32x64 output, 8 MFMA tiles, 2 per wave ----
    {
        const int mt  = wv & 1;
        const int ntb = (wv >> 1) * 2;
        f32x4 acc[2];
#pragma unroll
        for (int t = 0; t < 2; ++t) acc[t] = (f32x4)0.0f;

#pragma unroll
        for (int k0 = 0; k0 < 128; k0 += 32) {
            bf16x8 af = *(const bf16x8*)&sX[(mt * 16 + l16) * X1_ST + k0 + quad * 8];
#pragma unroll
            for (int t = 0; t < 2; ++t) {
                bf16x8 bf = *(const bf16x8*)&sW2[((ntb + t) * 16 + l16) * W2T_ST + k0 + quad * 8];
                acc[t] = __builtin_amdgcn_mfma_f32_16x16x32_bf16(af, bf, acc[t], 0, 0, 0);
            }
        }

#pragma unroll
        for (int t = 0; t < 2; ++t) {
            int col = (ntb + t) * 16 + l16;
#pragma unroll
            for (int r = 0; r < 4; ++r) {
                int lr = mt * 16 + quad * 4 + r;
                int gr = row0 + lr;
                if (gr < N)
                    hs2[(size_t)gr * 64 + col] = f32_to_bf16(acc[t][r] * sdv[lr]);
            }
        }
    }
}

static inline size_t align_up(size_t x, size_t a) { return (x + a - 1) / a * a; }

extern "C" void kernel_launch(void* const* d_in, const int* in_sizes, int n_in,
                              void* d_out, int out_size, void* d_ws, size_t ws_size,
                              hipStream_t stream) {
    const float* z    = (const float*)d_in[0];   // [N,64]
    const int*   eidx = (const int*)d_in[1];     // [2,E]: src row then dst row
    const float* W1   = (const float*)d_in[2];   // [64,128]
    const float* b1   = (const float*)d_in[3];   // [128]
    const float* W2   = (const float*)d_in[4];   // [128,64]
    const float* b2   = (const float*)d_in[5];   // [64]
    float* out = (float*)d_out;                  // [N,64]

    const int N = in_sizes[0] / 64;
    const int E = in_sizes[1] / 2;
    const int* src = eidx;
    const int* dst = eidx + E;
    const int NB = (N + NPB - 1) >> BSHIFT;      // 391 for N=100000

    // Workspace: small arrays | W1t | W2t | csr | bufA | bufB | bufC
    // u (bf16, N+1 rows incl. zero row) in bufA; agg1 (bf16) in bufB;
    // hs2 (bf16) overwrites u rows 0..N-1 in bufA -- row N (zero) survives
    // as the POST gather's tail target. ebuf (u32) aliases bufC.
    char* ws = (char*)d_ws;
    size_t off = 0;
    float* dinv    = (float*)(ws + off); off = align_up(off + (size_t)N * 4, 512);
    int*   rbeg    = (int*)  (ws + off); off = align_up(off + (size_t)N * 4, 512);
    int*   rend    = (int*)  (ws + off); off = align_up(off + (size_t)N * 4, 512);
    int*   bcursor = (int*)  (ws + off); off = align_up(off + (size_t)NBMAX * 4, 512);
    unsigned short* W1t = (unsigned short*)(ws + off); off = align_up(off + 8192 * 2, 512);
    unsigned short* W2t = (unsigned short*)(ws + off); off = align_up(off + 8192 * 2, 512);
    int*   csr     = (int*)  (ws + off); off = align_up(off + (size_t)NB * CAP * 4, 512);
    float* bufA    = (float*)(ws + off); off = align_up(off + (size_t)N * 64 * 4, 512);
    float* bufB    = (float*)(ws + off); off = align_up(off + (size_t)N * 64 * 4, 512);
    float* bufC    = (float*)(ws + off); off = align_up(off + (size_t)N * 128 * 4, 512);
    (void)ws_size;

    unsigned short* u    = (unsigned short*)bufA;   // bf16 z*dinv, rows 0..N (N = zero)
    unsigned short* agg1 = (unsigned short*)bufB;   // bf16 aggregated u
    unsigned short* hs2  = (unsigned short*)bufA;   // bf16 layer-2 pre-aggregate
    unsigned int*   ebuf = (unsigned int*)bufC;

    // ---- prep (cursor zero + W transpose/convert + zero row of u) ----
    prep<<<32, 256, 0, stream>>>(W1, W2, W1t, W2t, bcursor, NB, u, N);

    // ---- CSR build (+ fused dinv & u-scale) ----
    bin_edges<<<(E + CH - 1) / CH, BT, 0, stream>>>(src, dst, bcursor, ebuf, E, NB);
    build_csr<<<NB, 256, 0, stream>>>(ebuf, bcursor, z, dinv, rbeg, rend, csr, u, N);

    // ---- layer 1 aggregate (1 node/wave, 16-wide zero-row gather, NT out) ----
    aggregate64_bf16<false><<<(N + 3) / 4, 256, 0, stream>>>(u, rbeg, rend, csr, dinv, nullptr, agg1, N);

    // ---- fused dual GEMM on MFMA (x1 never leaves LDS) ----
    gemm12_mfma<<<(N + TILE - 1) / TILE, 256, 0, stream>>>(agg1, W1t, b1, W2t, dinv, hs2, N);

    // ---- layer 2 aggregate (1 node/wave, fp32 NT out) ----
    aggregate64_bf16<true><<<(N + 3) / 4, 256, 0, stream>>>(hs2, rbeg, rend, csr, dinv, b2, out, N);
}